// Round 1
// baseline (1096.477 us; speedup 1.0000x reference)
//
#include <hip/hip_runtime.h>

// GraphConv GNN forward, MI355X.
// N=50000 nodes, E=800000 edges, F_IN=128, H=64, G=64 graphs.
// Strategy: CSR build (no-atomic gather aggregation), min-dim edge aggregation,
// head folded into layer 4 (1 float/edge for L4), fused fp32 layer GEMMs.

#define NNODES 50000
#define NEDGES 800000
#define NGRAPH 64

// ---------------- CSR build ----------------

__global__ void deg_kernel(const int* __restrict__ dst, int* __restrict__ deg, int E) {
    int e = blockIdx.x * blockDim.x + threadIdx.x;
    if (e < E) atomicAdd(&deg[dst[e]], 1);
}

__global__ void scan_kernel(const int* __restrict__ deg, int* __restrict__ rp, int N) {
    __shared__ int buf[1024];
    __shared__ int carry;
    int tid = threadIdx.x;
    if (tid == 0) carry = 0;
    __syncthreads();
    for (int base = 0; base < N; base += 1024) {
        int i = base + tid;
        int v = (i < N) ? deg[i] : 0;
        buf[tid] = v;
        __syncthreads();
        for (int off = 1; off < 1024; off <<= 1) {
            int t = (tid >= off) ? buf[tid - off] : 0;
            __syncthreads();
            buf[tid] += t;
            __syncthreads();
        }
        int incl = buf[tid];
        int total = buf[1023];
        int c = carry;
        if (i < N) rp[i] = c + incl - v;   // exclusive
        __syncthreads();
        if (tid == 0) carry = c + total;
        __syncthreads();
    }
    if (tid == 0) rp[N] = carry;
}

__global__ void fill_kernel(const int* __restrict__ src, const int* __restrict__ dst,
                            const int* __restrict__ rp, int* __restrict__ fill,
                            int* __restrict__ csr, int E) {
    int e = blockIdx.x * blockDim.x + threadIdx.x;
    if (e >= E) return;
    int d = dst[e];
    int pos = atomicAdd(&fill[d], 1);
    csr[rp[d] + pos] = src[e];
}

// ---------------- per-node neighbor-sum (gather via CSR), F in {64,128} ----------------

__global__ void agg_kernel(const float* __restrict__ X, const int* __restrict__ rp,
                           const int* __restrict__ csr, float* __restrict__ out,
                           int N, int F) {
    int lane = threadIdx.x & 63;
    int node = (blockIdx.x * blockDim.x + threadIdx.x) >> 6;  // one wave per node
    if (node >= N) return;
    int e0 = rp[node], e1 = rp[node + 1];
    float a0 = 0.f, a1 = 0.f;
    for (int e = e0; e < e1; e++) {
        int s = csr[e];
        const float* row = X + (long)s * F;
        a0 += row[lane];
        if (F == 128) a1 += row[64 + lane];
    }
    out[(long)node * F + lane] = a0;
    if (F == 128) out[(long)node * F + 64 + lane] = a1;
}

// ---------------- fused layer GEMM ----------------
// out[n,o] = act( sum_k A[n,k] Wa[k,o] + (B ? sum_k B[n,k] Wb[k,o] : 0)
//                 + (Cadd ? Cadd[n,o] : 0) + (bias ? bias[o] : 0) )
// blockDim = (dout, NPB); LDS stages A (and B) rows for NPB nodes.

__global__ void layer_kernel(const float* __restrict__ A, const float* __restrict__ Wa,
                             const float* __restrict__ B, const float* __restrict__ Wb,
                             const float* __restrict__ Cadd, const float* __restrict__ bias,
                             float* __restrict__ out, int N, int K, int dout, int relu_flag) {
    extern __shared__ float smem[];
    const int NPB = blockDim.y;
    float* sA = smem;
    float* sB = smem + NPB * K;
    int nbase = blockIdx.x * NPB;
    int tid = threadIdx.y * blockDim.x + threadIdx.x;
    int nthreads = blockDim.x * blockDim.y;
    int totalA = NPB * K;
    for (int idx = tid; idx < totalA; idx += nthreads) {
        int r = idx / K, c = idx - (idx / K) * K;
        int n = nbase + r;
        float av = (n < N) ? A[(long)n * K + c] : 0.f;
        sA[idx] = av;
        if (B) sB[idx] = (n < N) ? B[(long)n * K + c] : 0.f;
    }
    __syncthreads();
    int n = nbase + threadIdx.y;
    if (n >= N) return;
    int o = threadIdx.x;
    float acc = bias ? bias[o] : 0.f;
    if (Cadd) acc += Cadd[(long)n * dout + o];
    const float* a = sA + threadIdx.y * K;
    #pragma unroll 4
    for (int k = 0; k < K; k++) acc = fmaf(a[k], Wa[k * dout + o], acc);
    if (B) {
        const float* b = sB + threadIdx.y * K;
        #pragma unroll 4
        for (int k = 0; k < K; k++) acc = fmaf(b[k], Wb[k * dout + o], acc);
    }
    if (relu_flag) acc = fmaxf(acc, 0.f);
    out[(long)n * dout + o] = acc;
}

// ---------------- layer-4 folding: wr = w4_rel@head_w, wt = w4_root@head_w ----------------

__global__ void wrwt_kernel(const float* __restrict__ w4_rel, const float* __restrict__ w4_root,
                            const float* __restrict__ b4, const float* __restrict__ head_w,
                            float* __restrict__ wr, float* __restrict__ wt, float* __restrict__ cbuf) {
    int tid = threadIdx.x;
    if (tid < 192) {
        float ar = 0.f, at = 0.f;
        for (int j = 0; j < 64; j++) {
            float hw = head_w[j];
            ar = fmaf(w4_rel[tid * 64 + j], hw, ar);
            at = fmaf(w4_root[tid * 64 + j], hw, at);
        }
        wr[tid] = ar;
        wt[tid] = at;
    } else if (tid == 192) {
        float c = 0.f;
        for (int j = 0; j < 64; j++) c = fmaf(b4[j], head_w[j], c);
        cbuf[0] = c;
    }
}

// s[n] = h3[n,:]·wr, t[n] = h3[n,:]·wt   (one wave per node, 192 = 3*64)
__global__ void st_kernel(const float* __restrict__ h3, const float* __restrict__ wr,
                          const float* __restrict__ wt, float* __restrict__ s,
                          float* __restrict__ t, int N) {
    int lane = threadIdx.x & 63;
    int node = (blockIdx.x * blockDim.x + threadIdx.x) >> 6;
    if (node >= N) return;
    const float* row = h3 + (long)node * 192;
    float as = 0.f, at = 0.f;
    #pragma unroll
    for (int v = 0; v < 3; v++) {
        float x = row[v * 64 + lane];
        as = fmaf(x, wr[v * 64 + lane], as);
        at = fmaf(x, wt[v * 64 + lane], at);
    }
    #pragma unroll
    for (int off = 32; off > 0; off >>= 1) {
        as += __shfl_down(as, off, 64);
        at += __shfl_down(at, off, 64);
    }
    if (lane == 0) { s[node] = as; t[node] = at; }
}

// agg_s[n] = sum over incoming neighbors of s[src]
__global__ void aggs_kernel(const float* __restrict__ s, const int* __restrict__ rp,
                            const int* __restrict__ csr, float* __restrict__ agg_s, int N) {
    int n = blockIdx.x * blockDim.x + threadIdx.x;
    if (n >= N) return;
    float a = 0.f;
    int e1 = rp[n + 1];
    for (int e = rp[n]; e < e1; e++) a += s[csr[e]];
    agg_s[n] = a;
}

// per-graph sums via LDS pre-reduction (batch is sorted, contention trivial)
__global__ void pool_kernel(const float* __restrict__ agg_s, const float* __restrict__ t,
                            const int* __restrict__ batch, float* __restrict__ gsum,
                            int* __restrict__ cnt, int N) {
    __shared__ float ls[NGRAPH];
    __shared__ int lc[NGRAPH];
    int tid = threadIdx.x;
    if (tid < NGRAPH) { ls[tid] = 0.f; lc[tid] = 0; }
    __syncthreads();
    int n = blockIdx.x * blockDim.x + tid;
    if (n < N) {
        int g = batch[n];
        atomicAdd(&ls[g], agg_s[n] + t[n]);
        atomicAdd(&lc[g], 1);
    }
    __syncthreads();
    if (tid < NGRAPH && lc[tid] > 0) {
        atomicAdd(&gsum[tid], ls[tid]);
        atomicAdd(&cnt[tid], lc[tid]);
    }
}

__global__ void final_kernel(const float* __restrict__ gsum, const int* __restrict__ cnt,
                             const float* __restrict__ cbuf, const float* __restrict__ head_b,
                             float* __restrict__ out) {
    int g = threadIdx.x;
    if (g < NGRAPH) {
        float c = (float)(cnt[g] > 1 ? cnt[g] : 1);
        out[g] = gsum[g] / c + cbuf[0] + head_b[0];
    }
}

// ---------------- launch ----------------

extern "C" void kernel_launch(void* const* d_in, const int* in_sizes, int n_in,
                              void* d_out, int out_size, void* d_ws, size_t ws_size,
                              hipStream_t stream) {
    const float* x       = (const float*)d_in[0];
    const int*   edge    = (const int*)d_in[1];   // (2,E) row-major: src then dst (int32; JAX x64 disabled)
    const int*   batch   = (const int*)d_in[2];
    const float* w1_rel  = (const float*)d_in[3];
    const float* w1_root = (const float*)d_in[4];
    const float* b1      = (const float*)d_in[5];
    const float* w2_rel  = (const float*)d_in[6];
    const float* w2_root = (const float*)d_in[7];
    const float* b2      = (const float*)d_in[8];
    const float* w3_rel  = (const float*)d_in[9];
    const float* w3_root = (const float*)d_in[10];
    const float* b3      = (const float*)d_in[11];
    const float* w4_rel  = (const float*)d_in[12];
    const float* w4_root = (const float*)d_in[13];
    const float* b4      = (const float*)d_in[14];
    const float* head_w  = (const float*)d_in[15];
    const float* head_b  = (const float*)d_in[16];
    float* out = (float*)d_out;

    const int N = NNODES, E = NEDGES;
    const int* src = edge;
    const int* dst = edge + E;

    // workspace carve-up (256B aligned)
    char* ws = (char*)d_ws;
    size_t off = 0;
    auto alloc = [&](size_t bytes) -> char* {
        char* p = ws + off;
        off = (off + bytes + 255) & ~(size_t)255;
        return p;
    };
    int*   deg    = (int*)alloc((size_t)N * 4);
    int*   rp     = (int*)alloc((size_t)(N + 1) * 4);
    int*   fill   = (int*)alloc((size_t)N * 4);
    int*   csr    = (int*)alloc((size_t)E * 4);
    float* aggbuf = (float*)alloc((size_t)N * 128 * 4);  // agg scratch (<=128 wide)
    float* y1     = (float*)alloc((size_t)N * 64 * 4);   // x @ w1_rel
    float* h1     = (float*)alloc((size_t)N * 64 * 4);
    float* h2     = (float*)alloc((size_t)N * 128 * 4);
    float* h3     = (float*)alloc((size_t)N * 192 * 4);
    float* sbuf   = (float*)alloc((size_t)N * 4);
    float* tbuf   = (float*)alloc((size_t)N * 4);
    float* asbuf  = (float*)alloc((size_t)N * 4);
    float* wr     = (float*)alloc(192 * 4);
    float* wt     = (float*)alloc(192 * 4);
    float* cbuf   = (float*)alloc(4);
    float* gsum   = (float*)alloc(NGRAPH * 4);
    int*   cnt    = (int*)alloc(NGRAPH * 4);
    (void)ws_size;

    hipMemsetAsync(deg, 0, (size_t)N * 4, stream);
    hipMemsetAsync(fill, 0, (size_t)N * 4, stream);
    hipMemsetAsync(gsum, 0, NGRAPH * 4, stream);
    hipMemsetAsync(cnt, 0, NGRAPH * 4, stream);

    const int TB = 256;
    int eblocks = (E + TB - 1) / TB;

    // CSR build
    deg_kernel<<<eblocks, TB, 0, stream>>>(dst, deg, E);
    scan_kernel<<<1, 1024, 0, stream>>>(deg, rp, N);
    fill_kernel<<<eblocks, TB, 0, stream>>>(src, dst, rp, fill, csr, E);

    // L1: y1 = x@w1_rel ; agg1 = nbr-sum(y1) ; h1 = relu(x@w1_root + agg1 + b1)
    {
        dim3 blk(64, 4);
        int grid = (N + 3) / 4;
        layer_kernel<<<grid, blk, 4 * 128 * 4, stream>>>(x, w1_rel, nullptr, nullptr,
                                                         nullptr, nullptr, y1, N, 128, 64, 0);
        agg_kernel<<<(N * 64 + TB - 1) / TB, TB, 0, stream>>>(y1, rp, csr, aggbuf, N, 64);
        layer_kernel<<<grid, blk, 4 * 128 * 4, stream>>>(x, w1_root, nullptr, nullptr,
                                                         aggbuf, b1, h1, N, 128, 64, 1);
    }
    // L2: agg2 = nbr-sum(h1) ; h2 = relu(agg2@w2_rel + h1@w2_root + b2)
    {
        agg_kernel<<<(N * 64 + TB - 1) / TB, TB, 0, stream>>>(h1, rp, csr, aggbuf, N, 64);
        dim3 blk(128, 2);
        int grid = (N + 1) / 2;
        layer_kernel<<<grid, blk, 2 * 2 * 64 * 4, stream>>>(aggbuf, w2_rel, h1, w2_root,
                                                            nullptr, b2, h2, N, 64, 128, 1);
    }
    // L3: agg3 = nbr-sum(h2) ; h3 = relu(agg3@w3_rel + h2@w3_root + b3)
    {
        agg_kernel<<<(N * 64 + TB - 1) / TB, TB, 0, stream>>>(h2, rp, csr, aggbuf, N, 128);
        dim3 blk(192, 1);
        layer_kernel<<<N, blk, 2 * 128 * 4, stream>>>(aggbuf, w3_rel, h2, w3_root,
                                                      nullptr, b3, h3, N, 128, 192, 1);
    }
    // L4 folded with head: s = h3@(w4_rel@head_w), t = h3@(w4_root@head_w)
    wrwt_kernel<<<1, 256, 0, stream>>>(w4_rel, w4_root, b4, head_w, wr, wt, cbuf);
    st_kernel<<<(N * 64 + TB - 1) / TB, TB, 0, stream>>>(h3, wr, wt, sbuf, tbuf, N);
    aggs_kernel<<<(N + TB - 1) / TB, TB, 0, stream>>>(sbuf, rp, csr, asbuf, N);
    pool_kernel<<<(N + TB - 1) / TB, TB, 0, stream>>>(asbuf, tbuf, batch, gsum, cnt, N);
    final_kernel<<<1, 64, 0, stream>>>(gsum, cnt, cbuf, head_b, out);
}

// Round 2
// 584.697 us; speedup vs baseline: 1.8753x; 1.8753x over previous
//
#include <hip/hip_runtime.h>

// GraphConv GNN forward, MI355X — Round 2: bf16 MFMA GEMMs.
// N=50000, E=800000, F_IN=128, H=64, G=64.
// - All layer GEMMs use v_mfma_f32_16x16x32_bf16 with weights pre-packed in
//   B-fragment order; activations stored bf16 row-major.
// - min-dim edge aggregation (L1 aggregates post-GEMM at width 64),
//   head folded into layer 4 (1 float/edge).
// - CSR gather aggregation (no atomics in hot path), bf16 rows, fp32 accum.

#define NNODES 50000
#define NEDGES 800000
#define NGRAPH 64

typedef __attribute__((ext_vector_type(8))) __bf16 bf16x8;
typedef __attribute__((ext_vector_type(4))) float f32x4;

__device__ __forceinline__ unsigned short f2bf(float f) {
    unsigned u = __float_as_uint(f);
    u += 0x7fff + ((u >> 16) & 1);   // RNE
    return (unsigned short)(u >> 16);
}
__device__ __forceinline__ float bf2f(unsigned b) {
    return __uint_as_float(b << 16);
}

// ---------------- CSR build ----------------

__global__ void deg_kernel(const int* __restrict__ dst, int* __restrict__ deg, int E) {
    int e = blockIdx.x * blockDim.x + threadIdx.x;
    if (e < E) atomicAdd(&deg[dst[e]], 1);
}

// single-block chunked exclusive scan: 49 serial adds + 10 barrier steps
__global__ void scan_kernel(const int* __restrict__ deg, int* __restrict__ rp, int N) {
    __shared__ int sums[1024];
    int tid = threadIdx.x;
    const int C = (N + 1023) / 1024;
    int base = tid * C;
    int s = 0;
    for (int j = 0; j < C; j++) { int i = base + j; if (i < N) s += deg[i]; }
    sums[tid] = s;
    __syncthreads();
    for (int off = 1; off < 1024; off <<= 1) {
        int v = (tid >= off) ? sums[tid - off] : 0;
        __syncthreads();
        sums[tid] += v;
        __syncthreads();
    }
    int run = (tid == 0) ? 0 : sums[tid - 1];
    for (int j = 0; j < C; j++) {
        int i = base + j;
        if (i < N) { rp[i] = run; run += deg[i]; }
    }
    if (tid == 1023) rp[N] = sums[1023];
}

__global__ void fill_kernel(const int* __restrict__ src, const int* __restrict__ dst,
                            const int* __restrict__ rp, int* __restrict__ fill,
                            int* __restrict__ csr, int E) {
    int e = blockIdx.x * blockDim.x + threadIdx.x;
    if (e >= E) return;
    int d = dst[e];
    int pos = atomicAdd(&fill[d], 1);
    csr[rp[d] + pos] = src[e];
}

// ---------------- fp32 -> bf16 conversion (x input) ----------------

__global__ void cvt_kernel(const float* __restrict__ src, unsigned short* __restrict__ dst, int n4) {
    int i = blockIdx.x * blockDim.x + threadIdx.x;
    if (i >= n4) return;
    float4 v = ((const float4*)src)[i];
    unsigned lo = (unsigned)f2bf(v.x) | ((unsigned)f2bf(v.y) << 16);
    unsigned hi = (unsigned)f2bf(v.z) | ((unsigned)f2bf(v.w) << 16);
    ((uint2*)dst)[i] = make_uint2(lo, hi);
}

// ---------------- weight packing into MFMA B-fragment order ----------------
// dst[((tg*KS + ks)*64 + lane)*8 + j] = bf16( W[k*dcols + col] )
//   k = ks*32 + (lane>>4)*8 + j ; col = tl*16 + (lane&15) ; tg = ct0 + tl

__global__ void pack_w_kernel(const float* __restrict__ W, unsigned short* __restrict__ dst,
                              int K, int dcols, int ct0, int ntiles) {
    int idx = blockIdx.x * blockDim.x + threadIdx.x;
    int KS = K >> 5;
    int total = ntiles * KS * 512;
    if (idx >= total) return;
    int j = idx & 7;
    int lane = (idx >> 3) & 63;
    int ks = (idx >> 9) % KS;
    int tl = (idx >> 9) / KS;
    int k = ks * 32 + (lane >> 4) * 8 + j;
    int col = tl * 16 + (lane & 15);
    int tg = ct0 + tl;
    dst[((size_t)(tg * KS + ks) * 64 + lane) * 8 + j] = f2bf(W[k * dcols + col]);
}

// ---------------- MFMA GEMM ----------------
// OUT[n,c] = act( sum_k A1[n,k] W1[k,c] (+ sum_k A2[n,k] W2[k,c]) + bias[c] )
// A row-major bf16 (ld = K), W pre-packed fragment order, OUT bf16 (ld = dout).
// Block = 256 threads (4 waves); wave computes 16 rows x dout cols.

template<int NT, int KS1, int KS2>
__global__ __launch_bounds__(256) void gemm_kernel(
    const unsigned short* __restrict__ A1, const unsigned short* __restrict__ W1,
    const unsigned short* __restrict__ A2, const unsigned short* __restrict__ W2,
    const float* __restrict__ bias, unsigned short* __restrict__ OUT,
    int relu, int N)
{
    const int dout = NT * 16;
    int tid = threadIdx.x;
    int wave = tid >> 6, lane = tid & 63;
    int quad = lane >> 4, l16 = lane & 15;
    int rbase = blockIdx.x * 64 + wave * 16;
    if (rbase >= N) return;

    f32x4 acc[NT];
    #pragma unroll
    for (int t = 0; t < NT; t++) acc[t] = (f32x4){0.f, 0.f, 0.f, 0.f};

    int arow = rbase + l16;
    if (arow >= N) arow = N - 1;   // clamp; garbage rows never stored

    {
        const int K1 = KS1 * 32;
        const unsigned short* abase = A1 + (size_t)arow * K1 + quad * 8;
        #pragma unroll
        for (int ks = 0; ks < KS1; ks++) {
            bf16x8 a = *(const bf16x8*)(abase + ks * 32);
            #pragma unroll
            for (int t = 0; t < NT; t++) {
                bf16x8 b = *(const bf16x8*)(W1 + ((size_t)(t * KS1 + ks) * 64 + lane) * 8);
                acc[t] = __builtin_amdgcn_mfma_f32_16x16x32_bf16(a, b, acc[t], 0, 0, 0);
            }
        }
    }
    if constexpr (KS2 > 0) {
        const int K2 = KS2 * 32;
        const unsigned short* abase = A2 + (size_t)arow * K2 + quad * 8;
        #pragma unroll
        for (int ks = 0; ks < KS2; ks++) {
            bf16x8 a = *(const bf16x8*)(abase + ks * 32);
            #pragma unroll
            for (int t = 0; t < NT; t++) {
                bf16x8 b = *(const bf16x8*)(W2 + ((size_t)(t * KS2 + ks) * 64 + lane) * 8);
                acc[t] = __builtin_amdgcn_mfma_f32_16x16x32_bf16(a, b, acc[t], 0, 0, 0);
            }
        }
    }

    // C/D layout: col = lane&15, row = quad*4 + reg   [verified m89/m91]
    #pragma unroll
    for (int t = 0; t < NT; t++) {
        int col = t * 16 + l16;
        float bi = bias ? bias[col] : 0.f;
        #pragma unroll
        for (int r = 0; r < 4; r++) {
            int n = rbase + quad * 4 + r;
            if (n < N) {
                float v = acc[t][r] + bi;
                if (relu) v = fmaxf(v, 0.f);
                OUT[(size_t)n * dout + col] = f2bf(v);
            }
        }
    }
}

// ---------------- bf16 neighbor-sum via CSR gather ----------------
// LPN lanes per node, each lane owns a bf16 feature pair. Optional fused
// root-term + bias + relu epilogue (used by L1).

template<int LPN>
__global__ void agg_kernel_bf(const unsigned short* __restrict__ X, int ldx,
                              const int* __restrict__ rp, const int* __restrict__ csr,
                              const unsigned short* __restrict__ root, int ldr,
                              const float* __restrict__ bias, int relu,
                              unsigned short* __restrict__ OUT, int ldo, int N) {
    int t = blockIdx.x * blockDim.x + threadIdx.x;
    int node = t / LPN;
    int sl = t % LPN;
    if (node >= N) return;
    float a0 = 0.f, a1 = 0.f;
    int e0 = rp[node], e1 = rp[node + 1];
    for (int e = e0; e < e1; e++) {
        int s = csr[e];
        unsigned u = *(const unsigned*)(X + (size_t)s * ldx + 2 * sl);
        a0 += bf2f(u & 0xffffu);
        a1 += bf2f(u >> 16);
    }
    if (root) {
        unsigned u = *(const unsigned*)(root + (size_t)node * ldr + 2 * sl);
        a0 += bf2f(u & 0xffffu);
        a1 += bf2f(u >> 16);
    }
    if (bias) { a0 += bias[2 * sl]; a1 += bias[2 * sl + 1]; }
    if (relu) { a0 = fmaxf(a0, 0.f); a1 = fmaxf(a1, 0.f); }
    unsigned o = (unsigned)f2bf(a0) | ((unsigned)f2bf(a1) << 16);
    *(unsigned*)(OUT + (size_t)node * ldo + 2 * sl) = o;
}

// ---------------- layer-4 head folding ----------------

__global__ void wrwt_kernel(const float* __restrict__ w4_rel, const float* __restrict__ w4_root,
                            const float* __restrict__ b4, const float* __restrict__ head_w,
                            float* __restrict__ wr, float* __restrict__ wt, float* __restrict__ cbuf) {
    int tid = threadIdx.x;
    if (tid < 192) {
        float ar = 0.f, at = 0.f;
        for (int j = 0; j < 64; j++) {
            float hw = head_w[j];
            ar = fmaf(w4_rel[tid * 64 + j], hw, ar);
            at = fmaf(w4_root[tid * 64 + j], hw, at);
        }
        wr[tid] = ar;
        wt[tid] = at;
    } else if (tid == 192) {
        float c = 0.f;
        for (int j = 0; j < 64; j++) c = fmaf(b4[j], head_w[j], c);
        cbuf[0] = c;
    }
}

// s[n] = h3[n,:]·wr, t[n] = h3[n,:]·wt  (h3 is bf16, 192 wide; one wave/node)
__global__ void st_kernel(const unsigned short* __restrict__ h3, const float* __restrict__ wr,
                          const float* __restrict__ wt, float* __restrict__ s,
                          float* __restrict__ t, int N) {
    int lane = threadIdx.x & 63;
    int node = (blockIdx.x * blockDim.x + threadIdx.x) >> 6;
    if (node >= N) return;
    const unsigned short* row = h3 + (size_t)node * 192;
    float as = 0.f, at = 0.f;
    #pragma unroll
    for (int v = 0; v < 3; v++) {
        float x = bf2f(row[v * 64 + lane]);
        as = fmaf(x, wr[v * 64 + lane], as);
        at = fmaf(x, wt[v * 64 + lane], at);
    }
    #pragma unroll
    for (int off = 32; off > 0; off >>= 1) {
        as += __shfl_down(as, off, 64);
        at += __shfl_down(at, off, 64);
    }
    if (lane == 0) { s[node] = as; t[node] = at; }
}

__global__ void aggs_kernel(const float* __restrict__ s, const int* __restrict__ rp,
                            const int* __restrict__ csr, float* __restrict__ agg_s, int N) {
    int n = blockIdx.x * blockDim.x + threadIdx.x;
    if (n >= N) return;
    float a = 0.f;
    int e1 = rp[n + 1];
    for (int e = rp[n]; e < e1; e++) a += s[csr[e]];
    agg_s[n] = a;
}

__global__ void pool_kernel(const float* __restrict__ agg_s, const float* __restrict__ t,
                            const int* __restrict__ batch, float* __restrict__ gsum,
                            int* __restrict__ cnt, int N) {
    __shared__ float ls[NGRAPH];
    __shared__ int lc[NGRAPH];
    int tid = threadIdx.x;
    if (tid < NGRAPH) { ls[tid] = 0.f; lc[tid] = 0; }
    __syncthreads();
    int n = blockIdx.x * blockDim.x + tid;
    if (n < N) {
        int g = batch[n];
        atomicAdd(&ls[g], agg_s[n] + t[n]);
        atomicAdd(&lc[g], 1);
    }
    __syncthreads();
    if (tid < NGRAPH && lc[tid] > 0) {
        atomicAdd(&gsum[tid], ls[tid]);
        atomicAdd(&cnt[tid], lc[tid]);
    }
}

__global__ void final_kernel(const float* __restrict__ gsum, const int* __restrict__ cnt,
                             const float* __restrict__ cbuf, const float* __restrict__ head_b,
                             float* __restrict__ out) {
    int g = threadIdx.x;
    if (g < NGRAPH) {
        float c = (float)(cnt[g] > 1 ? cnt[g] : 1);
        out[g] = gsum[g] / c + cbuf[0] + head_b[0];
    }
}

// ---------------- launch ----------------

extern "C" void kernel_launch(void* const* d_in, const int* in_sizes, int n_in,
                              void* d_out, int out_size, void* d_ws, size_t ws_size,
                              hipStream_t stream) {
    const float* x       = (const float*)d_in[0];
    const int*   edge    = (const int*)d_in[1];
    const int*   batch   = (const int*)d_in[2];
    const float* w1_rel  = (const float*)d_in[3];
    const float* w1_root = (const float*)d_in[4];
    const float* b1      = (const float*)d_in[5];
    const float* w2_rel  = (const float*)d_in[6];
    const float* w2_root = (const float*)d_in[7];
    const float* b2      = (const float*)d_in[8];
    const float* w3_rel  = (const float*)d_in[9];
    const float* w3_root = (const float*)d_in[10];
    const float* b3      = (const float*)d_in[11];
    const float* w4_rel  = (const float*)d_in[12];
    const float* w4_root = (const float*)d_in[13];
    const float* b4      = (const float*)d_in[14];
    const float* head_w  = (const float*)d_in[15];
    const float* head_b  = (const float*)d_in[16];
    float* out = (float*)d_out;

    const int N = NNODES, E = NEDGES;
    const int* src = edge;
    const int* dst = edge + E;

    char* ws = (char*)d_ws;
    size_t off = 0;
    auto alloc = [&](size_t bytes) -> char* {
        char* p = ws + off;
        off = (off + bytes + 255) & ~(size_t)255;
        return p;
    };
    int*   deg   = (int*)alloc((size_t)N * 4);
    int*   rp    = (int*)alloc((size_t)(N + 1) * 4);
    int*   fill  = (int*)alloc((size_t)N * 4);
    int*   csr   = (int*)alloc((size_t)E * 4);
    unsigned short* xbf    = (unsigned short*)alloc((size_t)N * 128 * 2);
    unsigned short* z1     = (unsigned short*)alloc((size_t)N * 128 * 2);  // [y=x@w1_rel | t=x@w1_root]
    unsigned short* h1     = (unsigned short*)alloc((size_t)N * 64 * 2);
    unsigned short* aggbuf = (unsigned short*)alloc((size_t)N * 128 * 2);
    unsigned short* h2     = (unsigned short*)alloc((size_t)N * 128 * 2);
    unsigned short* h3     = (unsigned short*)alloc((size_t)N * 192 * 2);
    unsigned short* pL1    = (unsigned short*)alloc(8 * 4 * 512 * 2);   // K=128, dout=128
    unsigned short* pL2a   = (unsigned short*)alloc(8 * 2 * 512 * 2);   // K=64, dout=128
    unsigned short* pL2b   = (unsigned short*)alloc(8 * 2 * 512 * 2);
    unsigned short* pL3a   = (unsigned short*)alloc(12 * 4 * 512 * 2);  // K=128, dout=192
    unsigned short* pL3b   = (unsigned short*)alloc(12 * 4 * 512 * 2);
    float* sbuf  = (float*)alloc((size_t)N * 4);
    float* tbuf  = (float*)alloc((size_t)N * 4);
    float* asbuf = (float*)alloc((size_t)N * 4);
    float* wr    = (float*)alloc(192 * 4);
    float* wt    = (float*)alloc(192 * 4);
    float* cbuf  = (float*)alloc(4);
    float* gsum  = (float*)alloc(NGRAPH * 4);
    int*   cnt   = (int*)alloc(NGRAPH * 4);
    (void)ws_size;

    hipMemsetAsync(deg, 0, (size_t)N * 4, stream);
    hipMemsetAsync(fill, 0, (size_t)N * 4, stream);
    hipMemsetAsync(gsum, 0, NGRAPH * 4, stream);
    hipMemsetAsync(cnt, 0, NGRAPH * 4, stream);

    const int TB = 256;
    int eblocks = (E + TB - 1) / TB;

    // CSR build
    deg_kernel<<<eblocks, TB, 0, stream>>>(dst, deg, E);
    scan_kernel<<<1, 1024, 0, stream>>>(deg, rp, N);
    fill_kernel<<<eblocks, TB, 0, stream>>>(src, dst, rp, fill, csr, E);

    // prep: convert x, pack weights, fold head
    cvt_kernel<<<(N * 128 / 4 + TB - 1) / TB, TB, 0, stream>>>(x, xbf, N * 128 / 4);
    pack_w_kernel<<<(4 * 4 * 512 + TB - 1) / TB, TB, 0, stream>>>(w1_rel, pL1, 128, 64, 0, 4);
    pack_w_kernel<<<(4 * 4 * 512 + TB - 1) / TB, TB, 0, stream>>>(w1_root, pL1, 128, 64, 4, 4);
    pack_w_kernel<<<(8 * 2 * 512 + TB - 1) / TB, TB, 0, stream>>>(w2_rel, pL2a, 64, 128, 0, 8);
    pack_w_kernel<<<(8 * 2 * 512 + TB - 1) / TB, TB, 0, stream>>>(w2_root, pL2b, 64, 128, 0, 8);
    pack_w_kernel<<<(12 * 4 * 512 + TB - 1) / TB, TB, 0, stream>>>(w3_rel, pL3a, 128, 192, 0, 12);
    pack_w_kernel<<<(12 * 4 * 512 + TB - 1) / TB, TB, 0, stream>>>(w3_root, pL3b, 128, 192, 0, 12);
    wrwt_kernel<<<1, 256, 0, stream>>>(w4_rel, w4_root, b4, head_w, wr, wt, cbuf);

    int gemm_grid = (N + 63) / 64;

    // L1: z1 = xbf @ [w1_rel | w1_root]   (dout=128, no bias/relu)
    gemm_kernel<8, 4, 0><<<gemm_grid, 256, 0, stream>>>(xbf, pL1, nullptr, nullptr,
                                                        nullptr, z1, 0, N);
    // h1 = relu( nbrsum(z1[:, :64]) + z1[:, 64:] + b1 )
    agg_kernel_bf<32><<<(N * 32 + TB - 1) / TB, TB, 0, stream>>>(z1, 128, rp, csr,
                                                                 z1 + 64, 128, b1, 1, h1, 64, N);
    // L2: agg2 = nbrsum(h1); h2 = relu(agg2@w2_rel + h1@w2_root + b2)
    agg_kernel_bf<32><<<(N * 32 + TB - 1) / TB, TB, 0, stream>>>(h1, 64, rp, csr,
                                                                 nullptr, 0, nullptr, 0, aggbuf, 64, N);
    gemm_kernel<8, 2, 2><<<gemm_grid, 256, 0, stream>>>(aggbuf, pL2a, h1, pL2b, b2, h2, 1, N);
    // L3: agg3 = nbrsum(h2); h3 = relu(agg3@w3_rel + h2@w3_root + b3)
    agg_kernel_bf<64><<<(N * 64 + TB - 1) / TB, TB, 0, stream>>>(h2, 128, rp, csr,
                                                                 nullptr, 0, nullptr, 0, aggbuf, 128, N);
    gemm_kernel<12, 4, 4><<<gemm_grid, 256, 0, stream>>>(aggbuf, pL3a, h2, pL3b, b3, h3, 1, N);

    // L4 folded with head
    st_kernel<<<(N * 64 + TB - 1) / TB, TB, 0, stream>>>(h3, wr, wt, sbuf, tbuf, N);
    aggs_kernel<<<(N + TB - 1) / TB, TB, 0, stream>>>(sbuf, rp, csr, asbuf, N);
    pool_kernel<<<(N + TB - 1) / TB, TB, 0, stream>>>(asbuf, tbuf, batch, gsum, cnt, N);
    final_kernel<<<1, 64, 0, stream>>>(gsum, cnt, cbuf, head_b, out);
}

// Round 3
// 415.638 us; speedup vs baseline: 2.6381x; 1.4067x over previous
//
#include <hip/hip_runtime.h>

// GraphConv GNN forward, MI355X — Round 3.
// R2 post-mortem: single-block scan was 95us (latency-bound, 1 CU). Replaced
// with 3-phase multi-block scan. Also merged 6 pack launches -> 1, 4 memsets
// -> 1, fused aggs+pool, vectorized gathers to 8B/lane.

#define NNODES 50000
#define NEDGES 800000
#define NGRAPH 64
#define SCAN_NB ((NNODES + 255) / 256)   // 196

typedef __attribute__((ext_vector_type(8))) __bf16 bf16x8;
typedef __attribute__((ext_vector_type(4))) float f32x4;

__device__ __forceinline__ unsigned short f2bf(float f) {
    unsigned u = __float_as_uint(f);
    u += 0x7fff + ((u >> 16) & 1);   // RNE
    return (unsigned short)(u >> 16);
}
__device__ __forceinline__ float bf2f(unsigned b) {
    return __uint_as_float(b << 16);
}

// ---------------- CSR build ----------------

__global__ void deg_kernel(const int* __restrict__ dst, int* __restrict__ deg, int E) {
    int e = blockIdx.x * blockDim.x + threadIdx.x;
    if (e < E) atomicAdd(&deg[dst[e]], 1);
}

// phase 1: per-256-block local exclusive scan + block totals
__global__ void scan1_kernel(const int* __restrict__ deg, int* __restrict__ rp,
                             int* __restrict__ bsum, int N) {
    __shared__ int buf[256];
    int tid = threadIdx.x;
    int i = blockIdx.x * 256 + tid;
    int v = (i < N) ? deg[i] : 0;
    buf[tid] = v;
    __syncthreads();
    #pragma unroll
    for (int off = 1; off < 256; off <<= 1) {
        int t = (tid >= off) ? buf[tid - off] : 0;
        __syncthreads();
        buf[tid] += t;
        __syncthreads();
    }
    if (i < N) rp[i] = buf[tid] - v;           // local exclusive
    if (tid == 255) bsum[blockIdx.x] = buf[255];
}

// phase 2: single block scans block totals (nb <= 256)
__global__ void scan2_kernel(int* __restrict__ bsum, int* __restrict__ rp, int nb, int N) {
    __shared__ int buf[256];
    int tid = threadIdx.x;
    int v = (tid < nb) ? bsum[tid] : 0;
    buf[tid] = v;
    __syncthreads();
    #pragma unroll
    for (int off = 1; off < 256; off <<= 1) {
        int t = (tid >= off) ? buf[tid - off] : 0;
        __syncthreads();
        buf[tid] += t;
        __syncthreads();
    }
    if (tid < nb) bsum[tid] = buf[tid] - v;    // exclusive block offsets
    if (tid == 255) rp[N] = buf[255];          // grand total
}

// phase 3: add block offsets
__global__ void scan3_kernel(int* __restrict__ rp, const int* __restrict__ bsum, int N) {
    int i = blockIdx.x * 256 + threadIdx.x;
    if (i < N) rp[i] += bsum[blockIdx.x];
}

__global__ void fill_kernel(const int* __restrict__ src, const int* __restrict__ dst,
                            const int* __restrict__ rp, int* __restrict__ fill,
                            int* __restrict__ csr, int E) {
    int e = blockIdx.x * blockDim.x + threadIdx.x;
    if (e >= E) return;
    int d = dst[e];
    int pos = atomicAdd(&fill[d], 1);
    csr[rp[d] + pos] = src[e];
}

// ---------------- fp32 -> bf16 conversion (x input) ----------------

__global__ void cvt_kernel(const float* __restrict__ src, unsigned short* __restrict__ dst, int n4) {
    int i = blockIdx.x * blockDim.x + threadIdx.x;
    if (i >= n4) return;
    float4 v = ((const float4*)src)[i];
    unsigned lo = (unsigned)f2bf(v.x) | ((unsigned)f2bf(v.y) << 16);
    unsigned hi = (unsigned)f2bf(v.z) | ((unsigned)f2bf(v.w) << 16);
    ((uint2*)dst)[i] = make_uint2(lo, hi);
}

// ---------------- weight packing into MFMA B-fragment order (all 6 in one) ----
// dst[((tg*KS + ks)*64 + lane)*8 + j] = bf16( W[k*dcols + col] )
//   k = ks*32 + (lane>>4)*8 + j ; col = tl*16 + (lane&15) ; tg = ct0 + tl

__device__ __forceinline__ void pack_elem(const float* __restrict__ W, unsigned short* __restrict__ dst,
                                          int KS, int dcols, int ct0, int gl, int lane, int j) {
    int ks = gl % KS, tl = gl / KS;
    int k = ks * 32 + (lane >> 4) * 8 + j;
    int col = tl * 16 + (lane & 15);
    int tg = ct0 + tl;
    dst[((size_t)(tg * KS + ks) * 64 + lane) * 8 + j] = f2bf(W[k * dcols + col]);
}

__global__ void pack_all_kernel(const float* __restrict__ w1_rel, const float* __restrict__ w1_root,
                                const float* __restrict__ w2_rel, const float* __restrict__ w2_root,
                                const float* __restrict__ w3_rel, const float* __restrict__ w3_root,
                                unsigned short* __restrict__ pL1, unsigned short* __restrict__ pL2a,
                                unsigned short* __restrict__ pL2b, unsigned short* __restrict__ pL3a,
                                unsigned short* __restrict__ pL3b) {
    int idx = blockIdx.x * blockDim.x + threadIdx.x;   // 160*512 total
    int g = idx >> 9;
    int t = idx & 511;
    int lane = (t >> 3) & 63, j = t & 7;
    if (g < 16)       pack_elem(w1_rel,  pL1,  4, 64,  0, g,       lane, j);
    else if (g < 32)  pack_elem(w1_root, pL1,  4, 64,  4, g - 16,  lane, j);
    else if (g < 48)  pack_elem(w2_rel,  pL2a, 2, 128, 0, g - 32,  lane, j);
    else if (g < 64)  pack_elem(w2_root, pL2b, 2, 128, 0, g - 48,  lane, j);
    else if (g < 112) pack_elem(w3_rel,  pL3a, 4, 192, 0, g - 64,  lane, j);
    else              pack_elem(w3_root, pL3b, 4, 192, 0, g - 112, lane, j);
}

// ---------------- MFMA GEMM ----------------
// OUT[n,c] = act( sum_k A1[n,k] W1[k,c] (+ sum_k A2[n,k] W2[k,c]) + bias[c] )

template<int NT, int KS1, int KS2>
__global__ __launch_bounds__(256) void gemm_kernel(
    const unsigned short* __restrict__ A1, const unsigned short* __restrict__ W1,
    const unsigned short* __restrict__ A2, const unsigned short* __restrict__ W2,
    const float* __restrict__ bias, unsigned short* __restrict__ OUT,
    int relu, int N)
{
    const int dout = NT * 16;
    int tid = threadIdx.x;
    int wave = tid >> 6, lane = tid & 63;
    int quad = lane >> 4, l16 = lane & 15;
    int rbase = blockIdx.x * 64 + wave * 16;
    if (rbase >= N) return;

    f32x4 acc[NT];
    #pragma unroll
    for (int t = 0; t < NT; t++) acc[t] = (f32x4){0.f, 0.f, 0.f, 0.f};

    int arow = rbase + l16;
    if (arow >= N) arow = N - 1;   // clamp; garbage rows never stored

    {
        const int K1 = KS1 * 32;
        const unsigned short* abase = A1 + (size_t)arow * K1 + quad * 8;
        #pragma unroll
        for (int ks = 0; ks < KS1; ks++) {
            bf16x8 a = *(const bf16x8*)(abase + ks * 32);
            #pragma unroll
            for (int t = 0; t < NT; t++) {
                bf16x8 b = *(const bf16x8*)(W1 + ((size_t)(t * KS1 + ks) * 64 + lane) * 8);
                acc[t] = __builtin_amdgcn_mfma_f32_16x16x32_bf16(a, b, acc[t], 0, 0, 0);
            }
        }
    }
    if constexpr (KS2 > 0) {
        const int K2 = KS2 * 32;
        const unsigned short* abase = A2 + (size_t)arow * K2 + quad * 8;
        #pragma unroll
        for (int ks = 0; ks < KS2; ks++) {
            bf16x8 a = *(const bf16x8*)(abase + ks * 32);
            #pragma unroll
            for (int t = 0; t < NT; t++) {
                bf16x8 b = *(const bf16x8*)(W2 + ((size_t)(t * KS2 + ks) * 64 + lane) * 8);
                acc[t] = __builtin_amdgcn_mfma_f32_16x16x32_bf16(a, b, acc[t], 0, 0, 0);
            }
        }
    }

    // C/D layout: col = lane&15, row = quad*4 + reg   [verified m89/m91]
    #pragma unroll
    for (int t = 0; t < NT; t++) {
        int col = t * 16 + l16;
        float bi = bias ? bias[col] : 0.f;
        #pragma unroll
        for (int r = 0; r < 4; r++) {
            int n = rbase + quad * 4 + r;
            if (n < N) {
                float v = acc[t][r] + bi;
                if (relu) v = fmaxf(v, 0.f);
                OUT[(size_t)n * dout + col] = f2bf(v);
            }
        }
    }
}

// ---------------- bf16 neighbor-sum via CSR gather ----------------
// LPN lanes per node, each lane owns 4 bf16 features (8B loads).

template<int LPN>
__global__ void agg_kernel_bf(const unsigned short* __restrict__ X, int ldx,
                              const int* __restrict__ rp, const int* __restrict__ csr,
                              const unsigned short* __restrict__ root, int ldr,
                              const float* __restrict__ bias, int relu,
                              unsigned short* __restrict__ OUT, int ldo, int N) {
    int t = blockIdx.x * blockDim.x + threadIdx.x;
    int node = t / LPN;
    int sl = t % LPN;
    if (node >= N) return;
    float a0 = 0.f, a1 = 0.f, a2 = 0.f, a3 = 0.f;
    int e0 = rp[node], e1 = rp[node + 1];
    for (int e = e0; e < e1; e++) {
        int s = csr[e];
        uint2 u = *(const uint2*)(X + (size_t)s * ldx + 4 * sl);
        a0 += bf2f(u.x & 0xffffu);
        a1 += bf2f(u.x >> 16);
        a2 += bf2f(u.y & 0xffffu);
        a3 += bf2f(u.y >> 16);
    }
    if (root) {
        uint2 u = *(const uint2*)(root + (size_t)node * ldr + 4 * sl);
        a0 += bf2f(u.x & 0xffffu);
        a1 += bf2f(u.x >> 16);
        a2 += bf2f(u.y & 0xffffu);
        a3 += bf2f(u.y >> 16);
    }
    if (bias) {
        const float4 b4 = *(const float4*)(bias + 4 * sl);
        a0 += b4.x; a1 += b4.y; a2 += b4.z; a3 += b4.w;
    }
    if (relu) {
        a0 = fmaxf(a0, 0.f); a1 = fmaxf(a1, 0.f);
        a2 = fmaxf(a2, 0.f); a3 = fmaxf(a3, 0.f);
    }
    uint2 o;
    o.x = (unsigned)f2bf(a0) | ((unsigned)f2bf(a1) << 16);
    o.y = (unsigned)f2bf(a2) | ((unsigned)f2bf(a3) << 16);
    *(uint2*)(OUT + (size_t)node * ldo + 4 * sl) = o;
}

// ---------------- layer-4 head folding ----------------

__global__ void wrwt_kernel(const float* __restrict__ w4_rel, const float* __restrict__ w4_root,
                            const float* __restrict__ b4, const float* __restrict__ head_w,
                            float* __restrict__ wr, float* __restrict__ wt, float* __restrict__ cbuf) {
    int tid = threadIdx.x;
    if (tid < 192) {
        float ar = 0.f, at = 0.f;
        for (int j = 0; j < 64; j++) {
            float hw = head_w[j];
            ar = fmaf(w4_rel[tid * 64 + j], hw, ar);
            at = fmaf(w4_root[tid * 64 + j], hw, at);
        }
        wr[tid] = ar;
        wt[tid] = at;
    } else if (tid == 192) {
        float c = 0.f;
        for (int j = 0; j < 64; j++) c = fmaf(b4[j], head_w[j], c);
        cbuf[0] = c;
    }
}

// s[n] = h3[n,:]·wr, t[n] = h3[n,:]·wt  (one wave/node, lanes 0..47 x 4 elems)
__global__ void st_kernel(const unsigned short* __restrict__ h3, const float* __restrict__ wr,
                          const float* __restrict__ wt, float* __restrict__ s,
                          float* __restrict__ t, int N) {
    int lane = threadIdx.x & 63;
    int node = (blockIdx.x * blockDim.x + threadIdx.x) >> 6;
    if (node >= N) return;
    float as = 0.f, at = 0.f;
    if (lane < 48) {
        uint2 u = *(const uint2*)(h3 + (size_t)node * 192 + 4 * lane);
        float x0 = bf2f(u.x & 0xffffu), x1 = bf2f(u.x >> 16);
        float x2 = bf2f(u.y & 0xffffu), x3 = bf2f(u.y >> 16);
        float4 r4 = *(const float4*)(wr + 4 * lane);
        float4 t4 = *(const float4*)(wt + 4 * lane);
        as = x0 * r4.x + x1 * r4.y + x2 * r4.z + x3 * r4.w;
        at = x0 * t4.x + x1 * t4.y + x2 * t4.z + x3 * t4.w;
    }
    #pragma unroll
    for (int off = 32; off > 0; off >>= 1) {
        as += __shfl_down(as, off, 64);
        at += __shfl_down(at, off, 64);
    }
    if (lane == 0) { s[node] = as; t[node] = at; }
}

// fused: agg_s[n] = sum s[nbr]; pool (a + t[n]) into per-graph sums + counts
__global__ void aggpool_kernel(const float* __restrict__ s, const float* __restrict__ t,
                               const int* __restrict__ rp, const int* __restrict__ csr,
                               const int* __restrict__ batch, float* __restrict__ gsum,
                               int* __restrict__ cnt, int N) {
    __shared__ float ls[NGRAPH];
    __shared__ int lc[NGRAPH];
    int tid = threadIdx.x;
    if (tid < NGRAPH) { ls[tid] = 0.f; lc[tid] = 0; }
    __syncthreads();
    int n = blockIdx.x * blockDim.x + tid;
    if (n < N) {
        float a = 0.f;
        int e1 = rp[n + 1];
        for (int e = rp[n]; e < e1; e++) a += s[csr[e]];
        int g = batch[n];
        atomicAdd(&ls[g], a + t[n]);
        atomicAdd(&lc[g], 1);
    }
    __syncthreads();
    if (tid < NGRAPH && lc[tid] > 0) {
        atomicAdd(&gsum[tid], ls[tid]);
        atomicAdd(&cnt[tid], lc[tid]);
    }
}

__global__ void final_kernel(const float* __restrict__ gsum, const int* __restrict__ cnt,
                             const float* __restrict__ cbuf, const float* __restrict__ head_b,
                             float* __restrict__ out) {
    int g = threadIdx.x;
    if (g < NGRAPH) {
        float c = (float)(cnt[g] > 0 ? cnt[g] : 1);
        out[g] = gsum[g] / c + cbuf[0] + head_b[0];
    }
}

// ---------------- launch ----------------

extern "C" void kernel_launch(void* const* d_in, const int* in_sizes, int n_in,
                              void* d_out, int out_size, void* d_ws, size_t ws_size,
                              hipStream_t stream) {
    const float* x       = (const float*)d_in[0];
    const int*   edge    = (const int*)d_in[1];
    const int*   batch   = (const int*)d_in[2];
    const float* w1_rel  = (const float*)d_in[3];
    const float* w1_root = (const float*)d_in[4];
    const float* b1      = (const float*)d_in[5];
    const float* w2_rel  = (const float*)d_in[6];
    const float* w2_root = (const float*)d_in[7];
    const float* b2      = (const float*)d_in[8];
    const float* w3_rel  = (const float*)d_in[9];
    const float* w3_root = (const float*)d_in[10];
    const float* b3      = (const float*)d_in[11];
    const float* w4_rel  = (const float*)d_in[12];
    const float* w4_root = (const float*)d_in[13];
    const float* b4      = (const float*)d_in[14];
    const float* head_w  = (const float*)d_in[15];
    const float* head_b  = (const float*)d_in[16];
    float* out = (float*)d_out;

    const int N = NNODES, E = NEDGES;
    const int* src = edge;
    const int* dst = edge + E;

    char* ws = (char*)d_ws;
    size_t off = 0;
    auto alloc = [&](size_t bytes) -> char* {
        char* p = ws + off;
        off = (off + bytes + 255) & ~(size_t)255;
        return p;
    };
    // zeroed region first (single memset): deg, fill, gsum, cnt
    int*   deg   = (int*)alloc((size_t)N * 4);
    int*   fill  = (int*)alloc((size_t)N * 4);
    float* gsum  = (float*)alloc(NGRAPH * 4);
    int*   cnt   = (int*)alloc(NGRAPH * 4);
    size_t zero_bytes = off;
    int*   rp    = (int*)alloc((size_t)(N + 1) * 4);
    int*   bsum  = (int*)alloc(256 * 4);
    int*   csr   = (int*)alloc((size_t)E * 4);
    unsigned short* xbf    = (unsigned short*)alloc((size_t)N * 128 * 2);
    unsigned short* z1     = (unsigned short*)alloc((size_t)N * 128 * 2);
    unsigned short* h1     = (unsigned short*)alloc((size_t)N * 64 * 2);
    unsigned short* aggbuf = (unsigned short*)alloc((size_t)N * 128 * 2);
    unsigned short* h2     = (unsigned short*)alloc((size_t)N * 128 * 2);
    unsigned short* h3     = (unsigned short*)alloc((size_t)N * 192 * 2);
    unsigned short* pL1    = (unsigned short*)alloc(8 * 4 * 512 * 2);
    unsigned short* pL2a   = (unsigned short*)alloc(8 * 2 * 512 * 2);
    unsigned short* pL2b   = (unsigned short*)alloc(8 * 2 * 512 * 2);
    unsigned short* pL3a   = (unsigned short*)alloc(12 * 4 * 512 * 2);
    unsigned short* pL3b   = (unsigned short*)alloc(12 * 4 * 512 * 2);
    float* sbuf  = (float*)alloc((size_t)N * 4);
    float* tbuf  = (float*)alloc((size_t)N * 4);
    float* wr    = (float*)alloc(192 * 4);
    float* wt    = (float*)alloc(192 * 4);
    float* cbuf  = (float*)alloc(4);
    (void)ws_size;

    hipMemsetAsync(deg, 0, zero_bytes, stream);

    const int TB = 256;
    int eblocks = (E + TB - 1) / TB;

    // CSR build (multi-block scan)
    deg_kernel<<<eblocks, TB, 0, stream>>>(dst, deg, E);
    scan1_kernel<<<SCAN_NB, 256, 0, stream>>>(deg, rp, bsum, N);
    scan2_kernel<<<1, 256, 0, stream>>>(bsum, rp, SCAN_NB, N);
    scan3_kernel<<<SCAN_NB, 256, 0, stream>>>(rp, bsum, N);
    fill_kernel<<<eblocks, TB, 0, stream>>>(src, dst, rp, fill, csr, E);

    // prep: convert x, pack all weights, fold head
    cvt_kernel<<<(N * 128 / 4 + TB - 1) / TB, TB, 0, stream>>>(x, xbf, N * 128 / 4);
    pack_all_kernel<<<160 * 512 / 256, 256, 0, stream>>>(w1_rel, w1_root, w2_rel, w2_root,
                                                         w3_rel, w3_root, pL1, pL2a, pL2b, pL3a, pL3b);
    wrwt_kernel<<<1, 256, 0, stream>>>(w4_rel, w4_root, b4, head_w, wr, wt, cbuf);

    int gemm_grid = (N + 63) / 64;

    // L1: z1 = xbf @ [w1_rel | w1_root]
    gemm_kernel<8, 4, 0><<<gemm_grid, 256, 0, stream>>>(xbf, pL1, nullptr, nullptr,
                                                        nullptr, z1, 0, N);
    // h1 = relu( nbrsum(z1[:, :64]) + z1[:, 64:] + b1 )
    agg_kernel_bf<16><<<(N * 16 + TB - 1) / TB, TB, 0, stream>>>(z1, 128, rp, csr,
                                                                 z1 + 64, 128, b1, 1, h1, 64, N);
    // L2
    agg_kernel_bf<16><<<(N * 16 + TB - 1) / TB, TB, 0, stream>>>(h1, 64, rp, csr,
                                                                 nullptr, 0, nullptr, 0, aggbuf, 64, N);
    gemm_kernel<8, 2, 2><<<gemm_grid, 256, 0, stream>>>(aggbuf, pL2a, h1, pL2b, b2, h2, 1, N);
    // L3
    agg_kernel_bf<32><<<(N * 32 + TB - 1) / TB, TB, 0, stream>>>(h2, 128, rp, csr,
                                                                 nullptr, 0, nullptr, 0, aggbuf, 128, N);
    gemm_kernel<12, 4, 4><<<gemm_grid, 256, 0, stream>>>(aggbuf, pL3a, h2, pL3b, b3, h3, 1, N);

    // L4 folded with head
    st_kernel<<<(N * 64 + TB - 1) / TB, TB, 0, stream>>>(h3, wr, wt, sbuf, tbuf, N);
    aggpool_kernel<<<(N + TB - 1) / TB, TB, 0, stream>>>(sbuf, tbuf, rp, csr, batch, gsum, cnt, N);
    final_kernel<<<1, 64, 0, stream>>>(gsum, cnt, cbuf, head_b, out);
}

// Round 4
// 403.516 us; speedup vs baseline: 2.7173x; 1.0300x over previous
//
#include <hip/hip_runtime.h>

// GraphConv GNN forward, MI355X — Round 4.
// R3 post-mortem: GEMMs latency-bound (VGPR=68 -> serialized B loads, MfmaUtil 3%).
// Fix: 32x32x16 MFMA, register-resident A frags (1-ahead dbuf), ks-outer/t-inner
// (NT indep acc chains), single combined A matrix + stacked packed weights per layer.

#define NNODES 50000
#define NEDGES 800000
#define NGRAPH 64
#define SCAN_NB ((NNODES + 255) / 256)   // 196

typedef __attribute__((ext_vector_type(8))) __bf16 bf16x8;
typedef __attribute__((ext_vector_type(16))) float f32x16;

__device__ __forceinline__ unsigned short f2bf(float f) {
    unsigned u = __float_as_uint(f);
    u += 0x7fff + ((u >> 16) & 1);   // RNE
    return (unsigned short)(u >> 16);
}
__device__ __forceinline__ float bf2f(unsigned b) {
    return __uint_as_float(b << 16);
}

// ---------------- CSR build ----------------

__global__ void deg_kernel(const int* __restrict__ dst, int* __restrict__ deg, int E) {
    int e = blockIdx.x * blockDim.x + threadIdx.x;
    if (e < E) atomicAdd(&deg[dst[e]], 1);
}

__global__ void scan1_kernel(const int* __restrict__ deg, int* __restrict__ rp,
                             int* __restrict__ bsum, int N) {
    __shared__ int buf[256];
    int tid = threadIdx.x;
    int i = blockIdx.x * 256 + tid;
    int v = (i < N) ? deg[i] : 0;
    buf[tid] = v;
    __syncthreads();
    #pragma unroll
    for (int off = 1; off < 256; off <<= 1) {
        int t = (tid >= off) ? buf[tid - off] : 0;
        __syncthreads();
        buf[tid] += t;
        __syncthreads();
    }
    if (i < N) rp[i] = buf[tid] - v;
    if (tid == 255) bsum[blockIdx.x] = buf[255];
}

__global__ void scan2_kernel(int* __restrict__ bsum, int* __restrict__ rp, int nb, int N) {
    __shared__ int buf[256];
    int tid = threadIdx.x;
    int v = (tid < nb) ? bsum[tid] : 0;
    buf[tid] = v;
    __syncthreads();
    #pragma unroll
    for (int off = 1; off < 256; off <<= 1) {
        int t = (tid >= off) ? buf[tid - off] : 0;
        __syncthreads();
        buf[tid] += t;
        __syncthreads();
    }
    if (tid < nb) bsum[tid] = buf[tid] - v;
    if (tid == 255) rp[N] = buf[255];
}

__global__ void scan3_kernel(int* __restrict__ rp, const int* __restrict__ bsum, int N) {
    int i = blockIdx.x * 256 + threadIdx.x;
    if (i < N) rp[i] += bsum[blockIdx.x];
}

__global__ void fill_kernel(const int* __restrict__ src, const int* __restrict__ dst,
                            const int* __restrict__ rp, int* __restrict__ fill,
                            int* __restrict__ csr, int E) {
    int e = blockIdx.x * blockDim.x + threadIdx.x;
    if (e >= E) return;
    int d = dst[e];
    int pos = atomicAdd(&fill[d], 1);
    csr[rp[d] + pos] = src[e];
}

// ---------------- fp32 -> bf16 conversion ----------------

__global__ void cvt_kernel(const float* __restrict__ src, unsigned short* __restrict__ dst, int n4) {
    int i = blockIdx.x * blockDim.x + threadIdx.x;
    if (i >= n4) return;
    float4 v = ((const float4*)src)[i];
    unsigned lo = (unsigned)f2bf(v.x) | ((unsigned)f2bf(v.y) << 16);
    unsigned hi = (unsigned)f2bf(v.z) | ((unsigned)f2bf(v.w) << 16);
    ((uint2*)dst)[i] = make_uint2(lo, hi);
}

// ---------------- weight packing: 32x32x16 B-fragment order, stacked K ----------
// B frag for (tile, ks): elem j of lane -> W[k = ks*16 + (lane>>5)*8 + j][col = tile*32 + (lane&31)]
// dst[((tile*KS_tot + ks)*64 + lane)*8 + j]

__device__ __forceinline__ void pack32(const float* __restrict__ W, unsigned short* __restrict__ dst,
                                       int KS_tot, int ks0, int dcols, int ct0,
                                       int tl, int ksl, int lane, int j) {
    int k = ksl * 16 + ((lane >> 5) << 3) + j;
    int col = tl * 32 + (lane & 31);
    dst[(((size_t)(ct0 + tl) * KS_tot + (ks0 + ksl)) * 64 + lane) * 8 + j] = f2bf(W[k * dcols + col]);
}

__global__ void pack_all_kernel(const float* __restrict__ w1_rel, const float* __restrict__ w1_root,
                                const float* __restrict__ w2_rel, const float* __restrict__ w2_root,
                                const float* __restrict__ w3_rel, const float* __restrict__ w3_root,
                                unsigned short* __restrict__ pL1, unsigned short* __restrict__ pL2,
                                unsigned short* __restrict__ pL3) {
    int idx = blockIdx.x * blockDim.x + threadIdx.x;   // 160 groups * 512
    int g = idx >> 9;
    int t = idx & 511;
    int lane = (t >> 3) & 63, j = t & 7;
    if (g < 16)       { int gl = g;       pack32(w1_rel,  pL1, 8,  0, 64,  0, gl / 8, gl % 8, lane, j); }
    else if (g < 32)  { int gl = g - 16;  pack32(w1_root, pL1, 8,  0, 64,  2, gl / 8, gl % 8, lane, j); }
    else if (g < 48)  { int gl = g - 32;  pack32(w2_rel,  pL2, 8,  0, 128, 0, gl / 4, gl % 4, lane, j); }
    else if (g < 64)  { int gl = g - 48;  pack32(w2_root, pL2, 8,  4, 128, 0, gl / 4, gl % 4, lane, j); }
    else if (g < 112) { int gl = g - 64;  pack32(w3_rel,  pL3, 16, 0, 192, 0, gl / 8, gl % 8, lane, j); }
    else              { int gl = g - 112; pack32(w3_root, pL3, 16, 8, 192, 0, gl / 8, gl % 8, lane, j); }
}

// ---------------- MFMA GEMM (32x32x16) ----------------
// OUT[n, ocol0+c] = act( sum_k A[n,k] W[k,c] + bias[c] ), A row-major bf16 (lda = K).
// Block = 4 waves x 32 rows = 128 rows. Wave: 32 rows x NT*32 cols.
// A frag: row = lane&31, k = (lane>>5)*8 + j. C/D: col = lane&31,
// row = (reg&3) + 8*(reg>>2) + 4*(lane>>5)   [verified m74/m101].

template<int NT, int KS>
__global__ __launch_bounds__(256) void gemm32_kernel(
    const unsigned short* __restrict__ A, const unsigned short* __restrict__ W,
    const float* __restrict__ bias, unsigned short* __restrict__ OUT,
    int ldo, int ocol0, int relu, int N)
{
    const int K = KS * 16;
    int tid = threadIdx.x;
    int wave = tid >> 6, lane = tid & 63;
    int l32 = lane & 31, half = lane >> 5;
    int rbase = blockIdx.x * 128 + wave * 32;
    if (rbase >= N) return;

    int arow = rbase + l32;
    if (arow >= N) arow = N - 1;   // clamp; garbage rows never stored
    const unsigned short* ab = A + (size_t)arow * K + half * 8;

    f32x16 acc[NT];
    #pragma unroll
    for (int t = 0; t < NT; t++)
        #pragma unroll
        for (int r = 0; r < 16; r++) acc[t][r] = 0.f;

    bf16x8 a_cur = *(const bf16x8*)(ab);
    #pragma unroll
    for (int ks = 0; ks < KS; ks++) {
        bf16x8 a_nxt;
        if (ks + 1 < KS) a_nxt = *(const bf16x8*)(ab + (ks + 1) * 16);
        #pragma unroll
        for (int t = 0; t < NT; t++) {
            bf16x8 b = *(const bf16x8*)(W + ((size_t)(t * KS + ks) * 64 + lane) * 8);
            acc[t] = __builtin_amdgcn_mfma_f32_32x32x16_bf16(a_cur, b, acc[t], 0, 0, 0);
        }
        a_cur = a_nxt;
    }

    #pragma unroll
    for (int t = 0; t < NT; t++) {
        int col = t * 32 + l32;
        float bi = bias ? bias[col] : 0.f;
        #pragma unroll
        for (int reg = 0; reg < 16; reg++) {
            int row = rbase + (reg & 3) + 8 * (reg >> 2) + 4 * half;
            if (row < N) {
                float v = acc[t][reg] + bi;
                if (relu) v = fmaxf(v, 0.f);
                OUT[(size_t)row * ldo + ocol0 + col] = f2bf(v);
            }
        }
    }
}

// ---------------- bf16 neighbor-sum via CSR gather ----------------

template<int LPN>
__global__ void agg_kernel_bf(const unsigned short* __restrict__ X, int ldx,
                              const int* __restrict__ rp, const int* __restrict__ csr,
                              const unsigned short* __restrict__ root, int ldr,
                              const float* __restrict__ bias, int relu,
                              unsigned short* __restrict__ OUT, int ldo, int N) {
    int t = blockIdx.x * blockDim.x + threadIdx.x;
    int node = t / LPN;
    int sl = t % LPN;
    if (node >= N) return;
    float a0 = 0.f, a1 = 0.f, a2 = 0.f, a3 = 0.f;
    int e0 = rp[node], e1 = rp[node + 1];
    for (int e = e0; e < e1; e++) {
        int s = csr[e];
        uint2 u = *(const uint2*)(X + (size_t)s * ldx + 4 * sl);
        a0 += bf2f(u.x & 0xffffu);
        a1 += bf2f(u.x >> 16);
        a2 += bf2f(u.y & 0xffffu);
        a3 += bf2f(u.y >> 16);
    }
    if (root) {
        uint2 u = *(const uint2*)(root + (size_t)node * ldr + 4 * sl);
        a0 += bf2f(u.x & 0xffffu);
        a1 += bf2f(u.x >> 16);
        a2 += bf2f(u.y & 0xffffu);
        a3 += bf2f(u.y >> 16);
    }
    if (bias) {
        const float4 b4 = *(const float4*)(bias + 4 * sl);
        a0 += b4.x; a1 += b4.y; a2 += b4.z; a3 += b4.w;
    }
    if (relu) {
        a0 = fmaxf(a0, 0.f); a1 = fmaxf(a1, 0.f);
        a2 = fmaxf(a2, 0.f); a3 = fmaxf(a3, 0.f);
    }
    uint2 o;
    o.x = (unsigned)f2bf(a0) | ((unsigned)f2bf(a1) << 16);
    o.y = (unsigned)f2bf(a2) | ((unsigned)f2bf(a3) << 16);
    *(uint2*)(OUT + (size_t)node * ldo + 4 * sl) = o;
}

// ---------------- layer-4 head folding ----------------

__global__ void wrwt_kernel(const float* __restrict__ w4_rel, const float* __restrict__ w4_root,
                            const float* __restrict__ b4, const float* __restrict__ head_w,
                            float* __restrict__ wr, float* __restrict__ wt, float* __restrict__ cbuf) {
    int tid = threadIdx.x;
    if (tid < 192) {
        float ar = 0.f, at = 0.f;
        for (int j = 0; j < 64; j++) {
            float hw = head_w[j];
            ar = fmaf(w4_rel[tid * 64 + j], hw, ar);
            at = fmaf(w4_root[tid * 64 + j], hw, at);
        }
        wr[tid] = ar;
        wt[tid] = at;
    } else if (tid == 192) {
        float c = 0.f;
        for (int j = 0; j < 64; j++) c = fmaf(b4[j], head_w[j], c);
        cbuf[0] = c;
    }
}

__global__ void st_kernel(const unsigned short* __restrict__ h3, const float* __restrict__ wr,
                          const float* __restrict__ wt, float* __restrict__ s,
                          float* __restrict__ t, int N) {
    int lane = threadIdx.x & 63;
    int node = (blockIdx.x * blockDim.x + threadIdx.x) >> 6;
    if (node >= N) return;
    float as = 0.f, at = 0.f;
    if (lane < 48) {
        uint2 u = *(const uint2*)(h3 + (size_t)node * 192 + 4 * lane);
        float x0 = bf2f(u.x & 0xffffu), x1 = bf2f(u.x >> 16);
        float x2 = bf2f(u.y & 0xffffu), x3 = bf2f(u.y >> 16);
        float4 r4 = *(const float4*)(wr + 4 * lane);
        float4 t4 = *(const float4*)(wt + 4 * lane);
        as = x0 * r4.x + x1 * r4.y + x2 * r4.z + x3 * r4.w;
        at = x0 * t4.x + x1 * t4.y + x2 * t4.z + x3 * t4.w;
    }
    #pragma unroll
    for (int off = 32; off > 0; off >>= 1) {
        as += __shfl_down(as, off, 64);
        at += __shfl_down(at, off, 64);
    }
    if (lane == 0) { s[node] = as; t[node] = at; }
}

__global__ void aggpool_kernel(const float* __restrict__ s, const float* __restrict__ t,
                               const int* __restrict__ rp, const int* __restrict__ csr,
                               const int* __restrict__ batch, float* __restrict__ gsum,
                               int* __restrict__ cnt, int N) {
    __shared__ float ls[NGRAPH];
    __shared__ int lc[NGRAPH];
    int tid = threadIdx.x;
    if (tid < NGRAPH) { ls[tid] = 0.f; lc[tid] = 0; }
    __syncthreads();
    int n = blockIdx.x * blockDim.x + tid;
    if (n < N) {
        float a = 0.f;
        int e1 = rp[n + 1];
        for (int e = rp[n]; e < e1; e++) a += s[csr[e]];
        int g = batch[n];
        atomicAdd(&ls[g], a + t[n]);
        atomicAdd(&lc[g], 1);
    }
    __syncthreads();
    if (tid < NGRAPH && lc[tid] > 0) {
        atomicAdd(&gsum[tid], ls[tid]);
        atomicAdd(&cnt[tid], lc[tid]);
    }
}

__global__ void final_kernel(const float* __restrict__ gsum, const int* __restrict__ cnt,
                             const float* __restrict__ cbuf, const float* __restrict__ head_b,
                             float* __restrict__ out) {
    int g = threadIdx.x;
    if (g < NGRAPH) {
        float c = (float)(cnt[g] > 0 ? cnt[g] : 1);
        out[g] = gsum[g] / c + cbuf[0] + head_b[0];
    }
}

// ---------------- launch ----------------

extern "C" void kernel_launch(void* const* d_in, const int* in_sizes, int n_in,
                              void* d_out, int out_size, void* d_ws, size_t ws_size,
                              hipStream_t stream) {
    const float* x       = (const float*)d_in[0];
    const int*   edge    = (const int*)d_in[1];
    const int*   batch   = (const int*)d_in[2];
    const float* w1_rel  = (const float*)d_in[3];
    const float* w1_root = (const float*)d_in[4];
    const float* b1      = (const float*)d_in[5];
    const float* w2_rel  = (const float*)d_in[6];
    const float* w2_root = (const float*)d_in[7];
    const float* b2      = (const float*)d_in[8];
    const float* w3_rel  = (const float*)d_in[9];
    const float* w3_root = (const float*)d_in[10];
    const float* b3      = (const float*)d_in[11];
    const float* w4_rel  = (const float*)d_in[12];
    const float* w4_root = (const float*)d_in[13];
    const float* b4      = (const float*)d_in[14];
    const float* head_w  = (const float*)d_in[15];
    const float* head_b  = (const float*)d_in[16];
    float* out = (float*)d_out;

    const int N = NNODES, E = NEDGES;
    const int* src = edge;
    const int* dst = edge + E;

    char* ws = (char*)d_ws;
    size_t off = 0;
    auto alloc = [&](size_t bytes) -> char* {
        char* p = ws + off;
        off = (off + bytes + 255) & ~(size_t)255;
        return p;
    };
    // zeroed region first (single memset): deg, fill, gsum, cnt
    int*   deg   = (int*)alloc((size_t)N * 4);
    int*   fill  = (int*)alloc((size_t)N * 4);
    float* gsum  = (float*)alloc(NGRAPH * 4);
    int*   cnt   = (int*)alloc(NGRAPH * 4);
    size_t zero_bytes = off;
    int*   rp    = (int*)alloc((size_t)(N + 1) * 4);
    int*   bsum  = (int*)alloc(256 * 4);
    int*   csr   = (int*)alloc((size_t)E * 4);
    unsigned short* xbf    = (unsigned short*)alloc((size_t)N * 128 * 2);
    unsigned short* z1     = (unsigned short*)alloc((size_t)N * 128 * 2);  // [x@w1_rel | x@w1_root]
    unsigned short* combo2 = (unsigned short*)alloc((size_t)N * 128 * 2);  // [agg2 | h1]
    unsigned short* combo3 = (unsigned short*)alloc((size_t)N * 256 * 2);  // [agg3 | h2]
    unsigned short* h3     = (unsigned short*)alloc((size_t)N * 192 * 2);
    unsigned short* pL1    = (unsigned short*)alloc(4 * 8 * 512 * 2);      // 32KB
    unsigned short* pL2    = (unsigned short*)alloc(4 * 8 * 512 * 2);      // 32KB
    unsigned short* pL3    = (unsigned short*)alloc(6 * 16 * 512 * 2);     // 96KB
    float* sbuf  = (float*)alloc((size_t)N * 4);
    float* tbuf  = (float*)alloc((size_t)N * 4);
    float* wr    = (float*)alloc(192 * 4);
    float* wt    = (float*)alloc(192 * 4);
    float* cbuf  = (float*)alloc(4);
    (void)ws_size;

    hipMemsetAsync(deg, 0, zero_bytes, stream);

    const int TB = 256;
    int eblocks = (E + TB - 1) / TB;

    // CSR build
    deg_kernel<<<eblocks, TB, 0, stream>>>(dst, deg, E);
    scan1_kernel<<<SCAN_NB, 256, 0, stream>>>(deg, rp, bsum, N);
    scan2_kernel<<<1, 256, 0, stream>>>(bsum, rp, SCAN_NB, N);
    scan3_kernel<<<SCAN_NB, 256, 0, stream>>>(rp, bsum, N);
    fill_kernel<<<eblocks, TB, 0, stream>>>(src, dst, rp, fill, csr, E);

    // prep
    cvt_kernel<<<(N * 128 / 4 + TB - 1) / TB, TB, 0, stream>>>(x, xbf, N * 128 / 4);
    pack_all_kernel<<<160 * 512 / 256, 256, 0, stream>>>(w1_rel, w1_root, w2_rel, w2_root,
                                                         w3_rel, w3_root, pL1, pL2, pL3);
    wrwt_kernel<<<1, 256, 0, stream>>>(w4_rel, w4_root, b4, head_w, wr, wt, cbuf);

    int ggrid = (N + 127) / 128;   // 391 blocks

    // L1: z1 = xbf @ [w1_rel | w1_root]  (no bias/relu here)
    gemm32_kernel<4, 8><<<ggrid, 256, 0, stream>>>(xbf, pL1, nullptr, z1, 128, 0, 0, N);
    // h1 = relu( nbrsum(z1[:,:64]) + z1[:,64:] + b1 )  -> combo2[:,64:]
    agg_kernel_bf<16><<<(N * 16 + TB - 1) / TB, TB, 0, stream>>>(z1, 128, rp, csr,
                                                                 z1 + 64, 128, b1, 1, combo2 + 64, 128, N);
    // agg2 = nbrsum(h1) -> combo2[:,:64]
    agg_kernel_bf<16><<<(N * 16 + TB - 1) / TB, TB, 0, stream>>>(combo2 + 64, 128, rp, csr,
                                                                 nullptr, 0, nullptr, 0, combo2, 128, N);
    // L2: h2 = relu(combo2 @ [w2_rel; w2_root] + b2) -> combo3[:,128:]
    gemm32_kernel<4, 8><<<ggrid, 256, 0, stream>>>(combo2, pL2, b2, combo3, 256, 128, 1, N);
    // agg3 = nbrsum(h2) -> combo3[:,:128]
    agg_kernel_bf<32><<<(N * 32 + TB - 1) / TB, TB, 0, stream>>>(combo3 + 128, 256, rp, csr,
                                                                 nullptr, 0, nullptr, 0, combo3, 256, N);
    // L3: h3 = relu(combo3 @ [w3_rel; w3_root] + b3)
    gemm32_kernel<6, 16><<<ggrid, 256, 0, stream>>>(combo3, pL3, b3, h3, 192, 0, 1, N);

    // L4 folded with head
    st_kernel<<<(N * 64 + TB - 1) / TB, TB, 0, stream>>>(h3, wr, wt, sbuf, tbuf, N);
    aggpool_kernel<<<(N + TB - 1) / TB, TB, 0, stream>>>(sbuf, tbuf, rp, csr, batch, gsum, cnt, N);
    final_kernel<<<1, 64, 0, stream>>>(gsum, cnt, cbuf, head_b, out);
}

// Round 5
// 347.464 us; speedup vs baseline: 3.1557x; 1.1613x over previous
//
#include <hip/hip_runtime.h>

// GraphConv GNN forward, MI355X — Round 5.
// R4 post-mortem: agg gather latency-bound (VGPR=12 -> 1 load in flight, VALU 16%).
// Fix: uint4 (16B) gathers, 2-way edge-split per node + 2x unroll (4 gathers in
// flight), shfl_xor combine; unrolled aggpool; merged prep (cvt+pack+wrwt).

#define NNODES 50000
#define NEDGES 800000
#define NGRAPH 64
#define SCAN_NB ((NNODES + 255) / 256)   // 196
#define CVT_NB (NNODES * 128 / 4 / 256)  // 6250
#define PACK_NB (160 * 512 / 256)        // 320

typedef __attribute__((ext_vector_type(8))) __bf16 bf16x8;
typedef __attribute__((ext_vector_type(16))) float f32x16;

__device__ __forceinline__ unsigned short f2bf(float f) {
    unsigned u = __float_as_uint(f);
    u += 0x7fff + ((u >> 16) & 1);   // RNE
    return (unsigned short)(u >> 16);
}
__device__ __forceinline__ float bf2f(unsigned b) {
    return __uint_as_float(b << 16);
}

// ---------------- CSR build ----------------

__global__ void deg_kernel(const int* __restrict__ dst, int* __restrict__ deg, int E) {
    int e = blockIdx.x * blockDim.x + threadIdx.x;
    if (e < E) atomicAdd(&deg[dst[e]], 1);
}

__global__ void scan1_kernel(const int* __restrict__ deg, int* __restrict__ rp,
                             int* __restrict__ bsum, int N) {
    __shared__ int buf[256];
    int tid = threadIdx.x;
    int i = blockIdx.x * 256 + tid;
    int v = (i < N) ? deg[i] : 0;
    buf[tid] = v;
    __syncthreads();
    #pragma unroll
    for (int off = 1; off < 256; off <<= 1) {
        int t = (tid >= off) ? buf[tid - off] : 0;
        __syncthreads();
        buf[tid] += t;
        __syncthreads();
    }
    if (i < N) rp[i] = buf[tid] - v;
    if (tid == 255) bsum[blockIdx.x] = buf[255];
}

__global__ void scan2_kernel(int* __restrict__ bsum, int* __restrict__ rp, int nb, int N) {
    __shared__ int buf[256];
    int tid = threadIdx.x;
    int v = (tid < nb) ? bsum[tid] : 0;
    buf[tid] = v;
    __syncthreads();
    #pragma unroll
    for (int off = 1; off < 256; off <<= 1) {
        int t = (tid >= off) ? buf[tid - off] : 0;
        __syncthreads();
        buf[tid] += t;
        __syncthreads();
    }
    if (tid < nb) bsum[tid] = buf[tid] - v;
    if (tid == 255) rp[N] = buf[255];
}

__global__ void scan3_kernel(int* __restrict__ rp, const int* __restrict__ bsum, int N) {
    int i = blockIdx.x * 256 + threadIdx.x;
    if (i < N) rp[i] += bsum[blockIdx.x];
}

__global__ void fill_kernel(const int* __restrict__ src, const int* __restrict__ dst,
                            const int* __restrict__ rp, int* __restrict__ fill,
                            int* __restrict__ csr, int E) {
    int e = blockIdx.x * blockDim.x + threadIdx.x;
    if (e >= E) return;
    int d = dst[e];
    int pos = atomicAdd(&fill[d], 1);
    csr[rp[d] + pos] = src[e];
}

// ---------------- merged prep: cvt + weight pack + head fold ----------------

__device__ __forceinline__ void pack32(const float* __restrict__ W, unsigned short* __restrict__ dst,
                                       int KS_tot, int ks0, int dcols, int ct0,
                                       int tl, int ksl, int lane, int j) {
    int k = ksl * 16 + ((lane >> 5) << 3) + j;
    int col = tl * 32 + (lane & 31);
    dst[(((size_t)(ct0 + tl) * KS_tot + (ks0 + ksl)) * 64 + lane) * 8 + j] = f2bf(W[k * dcols + col]);
}

__global__ void prep_kernel(const float* __restrict__ x, unsigned short* __restrict__ xbf,
                            const float* __restrict__ w1_rel, const float* __restrict__ w1_root,
                            const float* __restrict__ w2_rel, const float* __restrict__ w2_root,
                            const float* __restrict__ w3_rel, const float* __restrict__ w3_root,
                            unsigned short* __restrict__ pL1, unsigned short* __restrict__ pL2,
                            unsigned short* __restrict__ pL3,
                            const float* __restrict__ w4_rel, const float* __restrict__ w4_root,
                            const float* __restrict__ b4, const float* __restrict__ head_w,
                            float* __restrict__ wr, float* __restrict__ wt,
                            float* __restrict__ cbuf) {
    int b = blockIdx.x;
    int tid = threadIdx.x;
    if (b < CVT_NB) {                       // fp32 -> bf16 of x
        int i = b * 256 + tid;
        float4 v = ((const float4*)x)[i];
        unsigned lo = (unsigned)f2bf(v.x) | ((unsigned)f2bf(v.y) << 16);
        unsigned hi = (unsigned)f2bf(v.z) | ((unsigned)f2bf(v.w) << 16);
        ((uint2*)xbf)[i] = make_uint2(lo, hi);
    } else if (b < CVT_NB + PACK_NB) {      // weight packing (32x32x16 B-frag order)
        int idx = (b - CVT_NB) * 256 + tid;
        int g = idx >> 9;
        int t = idx & 511;
        int lane = (t >> 3) & 63, j = t & 7;
        if (g < 16)       { int gl = g;       pack32(w1_rel,  pL1, 8,  0, 64,  0, gl / 8, gl % 8, lane, j); }
        else if (g < 32)  { int gl = g - 16;  pack32(w1_root, pL1, 8,  0, 64,  2, gl / 8, gl % 8, lane, j); }
        else if (g < 48)  { int gl = g - 32;  pack32(w2_rel,  pL2, 8,  0, 128, 0, gl / 4, gl % 4, lane, j); }
        else if (g < 64)  { int gl = g - 48;  pack32(w2_root, pL2, 8,  4, 128, 0, gl / 4, gl % 4, lane, j); }
        else if (g < 112) { int gl = g - 64;  pack32(w3_rel,  pL3, 16, 0, 192, 0, gl / 8, gl % 8, lane, j); }
        else              { int gl = g - 112; pack32(w3_root, pL3, 16, 8, 192, 0, gl / 8, gl % 8, lane, j); }
    } else {                                // head folding
        if (tid < 192) {
            float ar = 0.f, at = 0.f;
            for (int j = 0; j < 64; j++) {
                float hw = head_w[j];
                ar = fmaf(w4_rel[tid * 64 + j], hw, ar);
                at = fmaf(w4_root[tid * 64 + j], hw, at);
            }
            wr[tid] = ar;
            wt[tid] = at;
        } else if (tid == 192) {
            float c = 0.f;
            for (int j = 0; j < 64; j++) c = fmaf(b4[j], head_w[j], c);
            cbuf[0] = c;
        }
    }
}

// ---------------- MFMA GEMM (32x32x16) ----------------
// A frag: row = lane&31, k = (lane>>5)*8 + j. C/D: col = lane&31,
// row = (reg&3) + 8*(reg>>2) + 4*(lane>>5)   [verified m74/m101].

template<int NT, int KS>
__global__ __launch_bounds__(256) void gemm32_kernel(
    const unsigned short* __restrict__ A, const unsigned short* __restrict__ W,
    const float* __restrict__ bias, unsigned short* __restrict__ OUT,
    int ldo, int ocol0, int relu, int N)
{
    const int K = KS * 16;
    int tid = threadIdx.x;
    int wave = tid >> 6, lane = tid & 63;
    int l32 = lane & 31, half = lane >> 5;
    int rbase = blockIdx.x * 128 + wave * 32;
    if (rbase >= N) return;

    int arow = rbase + l32;
    if (arow >= N) arow = N - 1;   // clamp; garbage rows never stored
    const unsigned short* ab = A + (size_t)arow * K + half * 8;

    f32x16 acc[NT];
    #pragma unroll
    for (int t = 0; t < NT; t++)
        #pragma unroll
        for (int r = 0; r < 16; r++) acc[t][r] = 0.f;

    bf16x8 a_cur = *(const bf16x8*)(ab);
    #pragma unroll
    for (int ks = 0; ks < KS; ks++) {
        bf16x8 a_nxt;
        if (ks + 1 < KS) a_nxt = *(const bf16x8*)(ab + (ks + 1) * 16);
        #pragma unroll
        for (int t = 0; t < NT; t++) {
            bf16x8 b = *(const bf16x8*)(W + ((size_t)(t * KS + ks) * 64 + lane) * 8);
            acc[t] = __builtin_amdgcn_mfma_f32_32x32x16_bf16(a_cur, b, acc[t], 0, 0, 0);
        }
        a_cur = a_nxt;
    }

    #pragma unroll
    for (int t = 0; t < NT; t++) {
        int col = t * 32 + l32;
        float bi = bias ? bias[col] : 0.f;
        #pragma unroll
        for (int reg = 0; reg < 16; reg++) {
            int row = rbase + (reg & 3) + 8 * (reg >> 2) + 4 * half;
            if (row < N) {
                float v = acc[t][reg] + bi;
                if (relu) v = fmaxf(v, 0.f);
                OUT[(size_t)row * ldo + ocol0 + col] = f2bf(v);
            }
        }
    }
}

// ---------------- bf16 neighbor-sum via CSR gather (v2: MLP) ----------------
// LPF feature lanes per node x 16B each; 2 edge sub-groups; 2x unroll ->
// 4 gathers in flight per lane. Combine subs with one shfl_xor.

__device__ __forceinline__ void acc8(float* a, uint4 u) {
    a[0] += bf2f(u.x & 0xffffu); a[1] += bf2f(u.x >> 16);
    a[2] += bf2f(u.y & 0xffffu); a[3] += bf2f(u.y >> 16);
    a[4] += bf2f(u.z & 0xffffu); a[5] += bf2f(u.z >> 16);
    a[6] += bf2f(u.w & 0xffffu); a[7] += bf2f(u.w >> 16);
}

template<int LPF>
__global__ void agg_kernel_v2(const unsigned short* __restrict__ X, int ldx,
                              const int* __restrict__ rp, const int* __restrict__ csr,
                              const unsigned short* __restrict__ root, int ldr,
                              const float* __restrict__ bias, int relu,
                              unsigned short* __restrict__ OUT, int ldo, int N) {
    int t = blockIdx.x * blockDim.x + threadIdx.x;
    int node = t / (2 * LPF);
    int r = t % (2 * LPF);
    int sub = r / LPF;
    int sl = r % LPF;
    if (node >= N) return;
    float a[8] = {0.f, 0.f, 0.f, 0.f, 0.f, 0.f, 0.f, 0.f};
    int e0 = rp[node], e1 = rp[node + 1];
    const unsigned short* xb = X + 8 * sl;
    int e = e0 + sub;
    for (; e + 2 < e1; e += 4) {          // this sub: edges e, e+2
        int s0 = csr[e], s1 = csr[e + 2];
        uint4 u0 = *(const uint4*)(xb + (size_t)s0 * ldx);
        uint4 u1 = *(const uint4*)(xb + (size_t)s1 * ldx);
        acc8(a, u0);
        acc8(a, u1);
    }
    if (e < e1) {
        uint4 u = *(const uint4*)(xb + (size_t)csr[e] * ldx);
        acc8(a, u);
    }
    #pragma unroll
    for (int i = 0; i < 8; i++) a[i] += __shfl_xor(a[i], LPF, 64);
    if (sub == 0) {
        if (root) {
            uint4 u = *(const uint4*)(root + (size_t)node * ldr + 8 * sl);
            acc8(a, u);
        }
        if (bias) {
            float4 b0 = *(const float4*)(bias + 8 * sl);
            float4 b1 = *(const float4*)(bias + 8 * sl + 4);
            a[0] += b0.x; a[1] += b0.y; a[2] += b0.z; a[3] += b0.w;
            a[4] += b1.x; a[5] += b1.y; a[6] += b1.z; a[7] += b1.w;
        }
        if (relu) {
            #pragma unroll
            for (int i = 0; i < 8; i++) a[i] = fmaxf(a[i], 0.f);
        }
        uint4 o;
        o.x = (unsigned)f2bf(a[0]) | ((unsigned)f2bf(a[1]) << 16);
        o.y = (unsigned)f2bf(a[2]) | ((unsigned)f2bf(a[3]) << 16);
        o.z = (unsigned)f2bf(a[4]) | ((unsigned)f2bf(a[5]) << 16);
        o.w = (unsigned)f2bf(a[6]) | ((unsigned)f2bf(a[7]) << 16);
        *(uint4*)(OUT + (size_t)node * ldo + 8 * sl) = o;
    }
}

// ---------------- layer-4 tail ----------------

__global__ void st_kernel(const unsigned short* __restrict__ h3, const float* __restrict__ wr,
                          const float* __restrict__ wt, float* __restrict__ s,
                          float* __restrict__ t, int N) {
    int lane = threadIdx.x & 63;
    int node = (blockIdx.x * blockDim.x + threadIdx.x) >> 6;
    if (node >= N) return;
    float as = 0.f, at = 0.f;
    if (lane < 48) {
        uint2 u = *(const uint2*)(h3 + (size_t)node * 192 + 4 * lane);
        float x0 = bf2f(u.x & 0xffffu), x1 = bf2f(u.x >> 16);
        float x2 = bf2f(u.y & 0xffffu), x3 = bf2f(u.y >> 16);
        float4 r4 = *(const float4*)(wr + 4 * lane);
        float4 t4 = *(const float4*)(wt + 4 * lane);
        as = x0 * r4.x + x1 * r4.y + x2 * r4.z + x3 * r4.w;
        at = x0 * t4.x + x1 * t4.y + x2 * t4.z + x3 * t4.w;
    }
    #pragma unroll
    for (int off = 32; off > 0; off >>= 1) {
        as += __shfl_down(as, off, 64);
        at += __shfl_down(at, off, 64);
    }
    if (lane == 0) { s[node] = as; t[node] = at; }
}

__global__ void aggpool_kernel(const float* __restrict__ s, const float* __restrict__ t,
                               const int* __restrict__ rp, const int* __restrict__ csr,
                               const int* __restrict__ batch, float* __restrict__ gsum,
                               int* __restrict__ cnt, int N) {
    __shared__ float ls[NGRAPH];
    __shared__ int lc[NGRAPH];
    int tid = threadIdx.x;
    if (tid < NGRAPH) { ls[tid] = 0.f; lc[tid] = 0; }
    __syncthreads();
    int n = blockIdx.x * blockDim.x + tid;
    if (n < N) {
        float a = 0.f;
        int e = rp[n], e1 = rp[n + 1];
        for (; e + 3 < e1; e += 4) {
            int s0 = csr[e], s1 = csr[e + 1], s2 = csr[e + 2], s3 = csr[e + 3];
            a += s[s0] + s[s1] + s[s2] + s[s3];
        }
        for (; e < e1; e++) a += s[csr[e]];
        int g = batch[n];
        atomicAdd(&ls[g], a + t[n]);
        atomicAdd(&lc[g], 1);
    }
    __syncthreads();
    if (tid < NGRAPH && lc[tid] > 0) {
        atomicAdd(&gsum[tid], ls[tid]);
        atomicAdd(&cnt[tid], lc[tid]);
    }
}

__global__ void final_kernel(const float* __restrict__ gsum, const int* __restrict__ cnt,
                             const float* __restrict__ cbuf, const float* __restrict__ head_b,
                             float* __restrict__ out) {
    int g = threadIdx.x;
    if (g < NGRAPH) {
        float c = (float)(cnt[g] > 0 ? cnt[g] : 1);
        out[g] = gsum[g] / c + cbuf[0] + head_b[0];
    }
}

// ---------------- launch ----------------

extern "C" void kernel_launch(void* const* d_in, const int* in_sizes, int n_in,
                              void* d_out, int out_size, void* d_ws, size_t ws_size,
                              hipStream_t stream) {
    const float* x       = (const float*)d_in[0];
    const int*   edge    = (const int*)d_in[1];
    const int*   batch   = (const int*)d_in[2];
    const float* w1_rel  = (const float*)d_in[3];
    const float* w1_root = (const float*)d_in[4];
    const float* b1      = (const float*)d_in[5];
    const float* w2_rel  = (const float*)d_in[6];
    const float* w2_root = (const float*)d_in[7];
    const float* b2      = (const float*)d_in[8];
    const float* w3_rel  = (const float*)d_in[9];
    const float* w3_root = (const float*)d_in[10];
    const float* b3      = (const float*)d_in[11];
    const float* w4_rel  = (const float*)d_in[12];
    const float* w4_root = (const float*)d_in[13];
    const float* b4      = (const float*)d_in[14];
    const float* head_w  = (const float*)d_in[15];
    const float* head_b  = (const float*)d_in[16];
    float* out = (float*)d_out;

    const int N = NNODES, E = NEDGES;
    const int* src = edge;
    const int* dst = edge + E;

    char* ws = (char*)d_ws;
    size_t off = 0;
    auto alloc = [&](size_t bytes) -> char* {
        char* p = ws + off;
        off = (off + bytes + 255) & ~(size_t)255;
        return p;
    };
    // zeroed region first (single memset): deg, fill, gsum, cnt
    int*   deg   = (int*)alloc((size_t)N * 4);
    int*   fill  = (int*)alloc((size_t)N * 4);
    float* gsum  = (float*)alloc(NGRAPH * 4);
    int*   cnt   = (int*)alloc(NGRAPH * 4);
    size_t zero_bytes = off;
    int*   rp    = (int*)alloc((size_t)(N + 1) * 4);
    int*   bsum  = (int*)alloc(256 * 4);
    int*   csr   = (int*)alloc((size_t)E * 4);
    unsigned short* xbf    = (unsigned short*)alloc((size_t)N * 128 * 2);
    unsigned short* z1     = (unsigned short*)alloc((size_t)N * 128 * 2);  // [x@w1_rel | x@w1_root]
    unsigned short* combo2 = (unsigned short*)alloc((size_t)N * 128 * 2);  // [agg2 | h1]
    unsigned short* combo3 = (unsigned short*)alloc((size_t)N * 256 * 2);  // [agg3 | h2]
    unsigned short* h3     = (unsigned short*)alloc((size_t)N * 192 * 2);
    unsigned short* pL1    = (unsigned short*)alloc(4 * 8 * 512 * 2);
    unsigned short* pL2    = (unsigned short*)alloc(4 * 8 * 512 * 2);
    unsigned short* pL3    = (unsigned short*)alloc(6 * 16 * 512 * 2);
    float* sbuf  = (float*)alloc((size_t)N * 4);
    float* tbuf  = (float*)alloc((size_t)N * 4);
    float* wr    = (float*)alloc(192 * 4);
    float* wt    = (float*)alloc(192 * 4);
    float* cbuf  = (float*)alloc(4);
    (void)ws_size;

    hipMemsetAsync(deg, 0, zero_bytes, stream);

    const int TB = 256;
    int eblocks = (E + TB - 1) / TB;

    // CSR build
    deg_kernel<<<eblocks, TB, 0, stream>>>(dst, deg, E);
    scan1_kernel<<<SCAN_NB, 256, 0, stream>>>(deg, rp, bsum, N);
    scan2_kernel<<<1, 256, 0, stream>>>(bsum, rp, SCAN_NB, N);
    scan3_kernel<<<SCAN_NB, 256, 0, stream>>>(rp, bsum, N);
    fill_kernel<<<eblocks, TB, 0, stream>>>(src, dst, rp, fill, csr, E);

    // prep (cvt + pack + head fold in one launch)
    prep_kernel<<<CVT_NB + PACK_NB + 1, 256, 0, stream>>>(
        x, xbf, w1_rel, w1_root, w2_rel, w2_root, w3_rel, w3_root,
        pL1, pL2, pL3, w4_rel, w4_root, b4, head_w, wr, wt, cbuf);

    int ggrid = (N + 127) / 128;

    // L1: z1 = xbf @ [w1_rel | w1_root]
    gemm32_kernel<4, 8><<<ggrid, 256, 0, stream>>>(xbf, pL1, nullptr, z1, 128, 0, 0, N);
    // h1 = relu( nbrsum(z1[:,:64]) + z1[:,64:] + b1 ) -> combo2[:,64:]
    agg_kernel_v2<8><<<(N * 16 + TB - 1) / TB, TB, 0, stream>>>(z1, 128, rp, csr,
                                                                z1 + 64, 128, b1, 1, combo2 + 64, 128, N);
    // agg2 = nbrsum(h1) -> combo2[:,:64]
    agg_kernel_v2<8><<<(N * 16 + TB - 1) / TB, TB, 0, stream>>>(combo2 + 64, 128, rp, csr,
                                                                nullptr, 0, nullptr, 0, combo2, 128, N);
    // L2: h2 = relu(combo2 @ [w2_rel; w2_root] + b2) -> combo3[:,128:]
    gemm32_kernel<4, 8><<<ggrid, 256, 0, stream>>>(combo2, pL2, b2, combo3, 256, 128, 1, N);
    // agg3 = nbrsum(h2) -> combo3[:,:128]
    agg_kernel_v2<16><<<(N * 32 + TB - 1) / TB, TB, 0, stream>>>(combo3 + 128, 256, rp, csr,
                                                                 nullptr, 0, nullptr, 0, combo3, 256, N);
    // L3: h3 = relu(combo3 @ [w3_rel; w3_root] + b3)
    gemm32_kernel<6, 16><<<ggrid, 256, 0, stream>>>(combo3, pL3, b3, h3, 192, 0, 1, N);

    // L4 folded with head
    st_kernel<<<(N * 64 + TB - 1) / TB, TB, 0, stream>>>(h3, wr, wt, sbuf, tbuf, N);
    aggpool_kernel<<<(N + TB - 1) / TB, TB, 0, stream>>>(sbuf, tbuf, rp, csr, batch, gsum, cnt, N);
    final_kernel<<<1, 64, 0, stream>>>(gsum, cnt, cbuf, head_b, out);
}

// Round 6
// 293.735 us; speedup vs baseline: 3.7329x; 1.1829x over previous
//
#include <hip/hip_runtime.h>

// GraphConv GNN forward, MI355X — Round 6.
// R5 post-mortem: fill_kernel 50us, WRITE_SIZE 55MB vs 3.2MB payload (16x write
// amplification from random 4B scatter). Fix: 256-bucket counting-sort CSR build
// (hist -> scan64k -> partition u64 pairs -> per-bucket L2-resident build).
// Removes deg_kernel + 50k scan entirely.

#define NNODES 50000
#define NEDGES 800000
#define NGRAPH 64
#define NBUK 256                          // dst buckets
#define BSZ 196                           // nodes per bucket (196*256 >= 50000)
#define EPB (NEDGES / NBUK)               // 3125 edges per partition block
#define CVT_NB (NNODES * 128 / 4 / 256)   // 6250
#define PACK_NB (160 * 512 / 256)         // 320

typedef __attribute__((ext_vector_type(8))) __bf16 bf16x8;
typedef __attribute__((ext_vector_type(16))) float f32x16;

__device__ __forceinline__ unsigned short f2bf(float f) {
    unsigned u = __float_as_uint(f);
    u += 0x7fff + ((u >> 16) & 1);   // RNE
    return (unsigned short)(u >> 16);
}
__device__ __forceinline__ float bf2f(unsigned b) {
    return __uint_as_float(b << 16);
}

// ---------------- CSR build: counting-sort partition ----------------

// Pass A: per-block 256-bucket histogram. cnt[bucket*NBUK + block].
__global__ void hist_kernel(const int* __restrict__ dst, int* __restrict__ cnt) {
    __shared__ int h[NBUK];
    int tid = threadIdx.x, k = blockIdx.x;
    h[tid] = 0;
    __syncthreads();
    int end = (k + 1) * EPB;
    for (int i = k * EPB + tid; i < end; i += 256)
        atomicAdd(&h[dst[i] / BSZ], 1);
    __syncthreads();
    cnt[tid * NBUK + k] = h[tid];
}

// generic 3-phase scan pieces (256-wide blocks)
__global__ void scan1_kernel(int* __restrict__ a, int* __restrict__ bsum, int n) {
    __shared__ int buf[256];
    int tid = threadIdx.x;
    int i = blockIdx.x * 256 + tid;
    int v = (i < n) ? a[i] : 0;
    buf[tid] = v;
    __syncthreads();
    #pragma unroll
    for (int off = 1; off < 256; off <<= 1) {
        int t = (tid >= off) ? buf[tid - off] : 0;
        __syncthreads();
        buf[tid] += t;
        __syncthreads();
    }
    if (i < n) a[i] = buf[tid] - v;            // local exclusive (in-place)
    if (tid == 255) bsum[blockIdx.x] = buf[255];
}

__global__ void scan2_kernel(int* __restrict__ bsum, int nb) {
    __shared__ int buf[256];
    int tid = threadIdx.x;
    int v = (tid < nb) ? bsum[tid] : 0;
    buf[tid] = v;
    __syncthreads();
    #pragma unroll
    for (int off = 1; off < 256; off <<= 1) {
        int t = (tid >= off) ? buf[tid - off] : 0;
        __syncthreads();
        buf[tid] += t;
        __syncthreads();
    }
    if (tid < nb) bsum[tid] = buf[tid] - v;    // exclusive block offsets
}

__global__ void scan3_kernel(int* __restrict__ a, const int* __restrict__ bsum, int n) {
    int i = blockIdx.x * 256 + threadIdx.x;
    if (i < n) a[i] += bsum[blockIdx.x];
}

// Pass C: partition edges into bucket-contiguous u64 (src | dst<<32) array.
__global__ void partition_kernel(const int* __restrict__ src, const int* __restrict__ dst,
                                 const int* __restrict__ cnt,
                                 unsigned long long* __restrict__ pedge) {
    __shared__ int lbase[NBUK];
    int tid = threadIdx.x, k = blockIdx.x;
    lbase[tid] = cnt[tid * NBUK + k];
    __syncthreads();
    int end = (k + 1) * EPB;
    for (int i = k * EPB + tid; i < end; i += 256) {
        int s = src[i], d = dst[i];
        int pos = atomicAdd(&lbase[d / BSZ], 1);
        pedge[pos] = (unsigned long long)(unsigned)s | ((unsigned long long)(unsigned)d << 32);
    }
}

// Pass D: one block per bucket — build rp + csr in an L2-resident 12.5KB region.
__global__ void build_kernel(const unsigned long long* __restrict__ pedge,
                             const int* __restrict__ cnt,
                             int* __restrict__ rp, int* __restrict__ csr) {
    __shared__ int sdeg[256], sc[256], sbase[256], sfill[256];
    int tid = threadIdx.x, b = blockIdx.x;
    int node0 = b * BSZ;
    int ncnt = NNODES - node0;
    if (ncnt > BSZ) ncnt = BSZ;
    if (ncnt < 0) ncnt = 0;
    int seg0 = cnt[b * NBUK];
    int seg1 = (b + 1 < NBUK) ? cnt[(b + 1) * NBUK] : NEDGES;
    sdeg[tid] = 0;
    sfill[tid] = 0;
    __syncthreads();
    for (int i = seg0 + tid; i < seg1; i += 256)
        atomicAdd(&sdeg[(int)(pedge[i] >> 32) - node0], 1);
    __syncthreads();
    sc[tid] = sdeg[tid];
    __syncthreads();
    #pragma unroll
    for (int off = 1; off < 256; off <<= 1) {
        int t = (tid >= off) ? sc[tid - off] : 0;
        __syncthreads();
        sc[tid] += t;
        __syncthreads();
    }
    sbase[tid] = sc[tid] - sdeg[tid];          // exclusive within bucket
    if (tid < ncnt) rp[node0 + tid] = seg0 + sbase[tid];
    if (b == NBUK - 1 && tid == 0) rp[NNODES] = NEDGES;
    __syncthreads();
    for (int i = seg0 + tid; i < seg1; i += 256) {
        unsigned long long p = pedge[i];
        int d = (int)(p >> 32) - node0;
        int pos = atomicAdd(&sfill[d], 1);
        csr[seg0 + sbase[d] + pos] = (int)(p & 0xffffffffu);
    }
}

// ---------------- merged prep: cvt + weight pack + head fold ----------------

__device__ __forceinline__ void pack32(const float* __restrict__ W, unsigned short* __restrict__ dst,
                                       int KS_tot, int ks0, int dcols, int ct0,
                                       int tl, int ksl, int lane, int j) {
    int k = ksl * 16 + ((lane >> 5) << 3) + j;
    int col = tl * 32 + (lane & 31);
    dst[(((size_t)(ct0 + tl) * KS_tot + (ks0 + ksl)) * 64 + lane) * 8 + j] = f2bf(W[k * dcols + col]);
}

__global__ void prep_kernel(const float* __restrict__ x, unsigned short* __restrict__ xbf,
                            const float* __restrict__ w1_rel, const float* __restrict__ w1_root,
                            const float* __restrict__ w2_rel, const float* __restrict__ w2_root,
                            const float* __restrict__ w3_rel, const float* __restrict__ w3_root,
                            unsigned short* __restrict__ pL1, unsigned short* __restrict__ pL2,
                            unsigned short* __restrict__ pL3,
                            const float* __restrict__ w4_rel, const float* __restrict__ w4_root,
                            const float* __restrict__ b4, const float* __restrict__ head_w,
                            float* __restrict__ wr, float* __restrict__ wt,
                            float* __restrict__ cbuf) {
    int b = blockIdx.x;
    int tid = threadIdx.x;
    if (b < CVT_NB) {                       // fp32 -> bf16 of x
        int i = b * 256 + tid;
        float4 v = ((const float4*)x)[i];
        unsigned lo = (unsigned)f2bf(v.x) | ((unsigned)f2bf(v.y) << 16);
        unsigned hi = (unsigned)f2bf(v.z) | ((unsigned)f2bf(v.w) << 16);
        ((uint2*)xbf)[i] = make_uint2(lo, hi);
    } else if (b < CVT_NB + PACK_NB) {      // weight packing (32x32x16 B-frag order)
        int idx = (b - CVT_NB) * 256 + tid;
        int g = idx >> 9;
        int t = idx & 511;
        int lane = (t >> 3) & 63, j = t & 7;
        if (g < 16)       { int gl = g;       pack32(w1_rel,  pL1, 8,  0, 64,  0, gl / 8, gl % 8, lane, j); }
        else if (g < 32)  { int gl = g - 16;  pack32(w1_root, pL1, 8,  0, 64,  2, gl / 8, gl % 8, lane, j); }
        else if (g < 48)  { int gl = g - 32;  pack32(w2_rel,  pL2, 8,  0, 128, 0, gl / 4, gl % 4, lane, j); }
        else if (g < 64)  { int gl = g - 48;  pack32(w2_root, pL2, 8,  4, 128, 0, gl / 4, gl % 4, lane, j); }
        else if (g < 112) { int gl = g - 64;  pack32(w3_rel,  pL3, 16, 0, 192, 0, gl / 8, gl % 8, lane, j); }
        else              { int gl = g - 112; pack32(w3_root, pL3, 16, 8, 192, 0, gl / 8, gl % 8, lane, j); }
    } else {                                // head folding
        if (tid < 192) {
            float ar = 0.f, at = 0.f;
            for (int j = 0; j < 64; j++) {
                float hw = head_w[j];
                ar = fmaf(w4_rel[tid * 64 + j], hw, ar);
                at = fmaf(w4_root[tid * 64 + j], hw, at);
            }
            wr[tid] = ar;
            wt[tid] = at;
        } else if (tid == 192) {
            float c = 0.f;
            for (int j = 0; j < 64; j++) c = fmaf(b4[j], head_w[j], c);
            cbuf[0] = c;
        }
    }
}

// ---------------- MFMA GEMM (32x32x16) ----------------
// A frag: row = lane&31, k = (lane>>5)*8 + j. C/D: col = lane&31,
// row = (reg&3) + 8*(reg>>2) + 4*(lane>>5)   [verified m74/m101].

template<int NT, int KS>
__global__ __launch_bounds__(256) void gemm32_kernel(
    const unsigned short* __restrict__ A, const unsigned short* __restrict__ W,
    const float* __restrict__ bias, unsigned short* __restrict__ OUT,
    int ldo, int ocol0, int relu, int N)
{
    const int K = KS * 16;
    int tid = threadIdx.x;
    int wave = tid >> 6, lane = tid & 63;
    int l32 = lane & 31, half = lane >> 5;
    int rbase = blockIdx.x * 128 + wave * 32;
    if (rbase >= N) return;

    int arow = rbase + l32;
    if (arow >= N) arow = N - 1;   // clamp; garbage rows never stored
    const unsigned short* ab = A + (size_t)arow * K + half * 8;

    f32x16 acc[NT];
    #pragma unroll
    for (int t = 0; t < NT; t++)
        #pragma unroll
        for (int r = 0; r < 16; r++) acc[t][r] = 0.f;

    bf16x8 a_cur = *(const bf16x8*)(ab);
    #pragma unroll
    for (int ks = 0; ks < KS; ks++) {
        bf16x8 a_nxt;
        if (ks + 1 < KS) a_nxt = *(const bf16x8*)(ab + (ks + 1) * 16);
        #pragma unroll
        for (int t = 0; t < NT; t++) {
            bf16x8 b = *(const bf16x8*)(W + ((size_t)(t * KS + ks) * 64 + lane) * 8);
            acc[t] = __builtin_amdgcn_mfma_f32_32x32x16_bf16(a_cur, b, acc[t], 0, 0, 0);
        }
        a_cur = a_nxt;
    }

    #pragma unroll
    for (int t = 0; t < NT; t++) {
        int col = t * 32 + l32;
        float bi = bias ? bias[col] : 0.f;
        #pragma unroll
        for (int reg = 0; reg < 16; reg++) {
            int row = rbase + (reg & 3) + 8 * (reg >> 2) + 4 * half;
            if (row < N) {
                float v = acc[t][reg] + bi;
                if (relu) v = fmaxf(v, 0.f);
                OUT[(size_t)row * ldo + ocol0 + col] = f2bf(v);
            }
        }
    }
}

// ---------------- bf16 neighbor-sum via CSR gather ----------------
// LPF feature lanes per node x 16B each; 2 edge sub-groups; 2x unroll ->
// 4 gathers in flight per lane. Combine subs with one shfl_xor.

__device__ __forceinline__ void acc8(float* a, uint4 u) {
    a[0] += bf2f(u.x & 0xffffu); a[1] += bf2f(u.x >> 16);
    a[2] += bf2f(u.y & 0xffffu); a[3] += bf2f(u.y >> 16);
    a[4] += bf2f(u.z & 0xffffu); a[5] += bf2f(u.z >> 16);
    a[6] += bf2f(u.w & 0xffffu); a[7] += bf2f(u.w >> 16);
}

template<int LPF>
__global__ void agg_kernel_v2(const unsigned short* __restrict__ X, int ldx,
                              const int* __restrict__ rp, const int* __restrict__ csr,
                              const unsigned short* __restrict__ root, int ldr,
                              const float* __restrict__ bias, int relu,
                              unsigned short* __restrict__ OUT, int ldo, int N) {
    int t = blockIdx.x * blockDim.x + threadIdx.x;
    int node = t / (2 * LPF);
    int r = t % (2 * LPF);
    int sub = r / LPF;
    int sl = r % LPF;
    if (node >= N) return;
    float a[8] = {0.f, 0.f, 0.f, 0.f, 0.f, 0.f, 0.f, 0.f};
    int e0 = rp[node], e1 = rp[node + 1];
    const unsigned short* xb = X + 8 * sl;
    int e = e0 + sub;
    for (; e + 2 < e1; e += 4) {          // this sub: edges e, e+2
        int s0 = csr[e], s1 = csr[e + 2];
        uint4 u0 = *(const uint4*)(xb + (size_t)s0 * ldx);
        uint4 u1 = *(const uint4*)(xb + (size_t)s1 * ldx);
        acc8(a, u0);
        acc8(a, u1);
    }
    if (e < e1) {
        uint4 u = *(const uint4*)(xb + (size_t)csr[e] * ldx);
        acc8(a, u);
    }
    #pragma unroll
    for (int i = 0; i < 8; i++) a[i] += __shfl_xor(a[i], LPF, 64);
    if (sub == 0) {
        if (root) {
            uint4 u = *(const uint4*)(root + (size_t)node * ldr + 8 * sl);
            acc8(a, u);
        }
        if (bias) {
            float4 b0 = *(const float4*)(bias + 8 * sl);
            float4 b1 = *(const float4*)(bias + 8 * sl + 4);
            a[0] += b0.x; a[1] += b0.y; a[2] += b0.z; a[3] += b0.w;
            a[4] += b1.x; a[5] += b1.y; a[6] += b1.z; a[7] += b1.w;
        }
        if (relu) {
            #pragma unroll
            for (int i = 0; i < 8; i++) a[i] = fmaxf(a[i], 0.f);
        }
        uint4 o;
        o.x = (unsigned)f2bf(a[0]) | ((unsigned)f2bf(a[1]) << 16);
        o.y = (unsigned)f2bf(a[2]) | ((unsigned)f2bf(a[3]) << 16);
        o.z = (unsigned)f2bf(a[4]) | ((unsigned)f2bf(a[5]) << 16);
        o.w = (unsigned)f2bf(a[6]) | ((unsigned)f2bf(a[7]) << 16);
        *(uint4*)(OUT + (size_t)node * ldo + 8 * sl) = o;
    }
}

// ---------------- layer-4 tail ----------------

__global__ void st_kernel(const unsigned short* __restrict__ h3, const float* __restrict__ wr,
                          const float* __restrict__ wt, float* __restrict__ s,
                          float* __restrict__ t, int N) {
    int lane = threadIdx.x & 63;
    int node = (blockIdx.x * blockDim.x + threadIdx.x) >> 6;
    if (node >= N) return;
    float as = 0.f, at = 0.f;
    if (lane < 48) {
        uint2 u = *(const uint2*)(h3 + (size_t)node * 192 + 4 * lane);
        float x0 = bf2f(u.x & 0xffffu), x1 = bf2f(u.x >> 16);
        float x2 = bf2f(u.y & 0xffffu), x3 = bf2f(u.y >> 16);
        float4 r4 = *(const float4*)(wr + 4 * lane);
        float4 t4 = *(const float4*)(wt + 4 * lane);
        as = x0 * r4.x + x1 * r4.y + x2 * r4.z + x3 * r4.w;
        at = x0 * t4.x + x1 * t4.y + x2 * t4.z + x3 * t4.w;
    }
    #pragma unroll
    for (int off = 32; off > 0; off >>= 1) {
        as += __shfl_down(as, off, 64);
        at += __shfl_down(at, off, 64);
    }
    if (lane == 0) { s[node] = as; t[node] = at; }
}

__global__ void aggpool_kernel(const float* __restrict__ s, const float* __restrict__ t,
                               const int* __restrict__ rp, const int* __restrict__ csr,
                               const int* __restrict__ batch, float* __restrict__ gsum,
                               int* __restrict__ cnt, int N) {
    __shared__ float ls[NGRAPH];
    __shared__ int lc[NGRAPH];
    int tid = threadIdx.x;
    if (tid < NGRAPH) { ls[tid] = 0.f; lc[tid] = 0; }
    __syncthreads();
    int n = blockIdx.x * blockDim.x + tid;
    if (n < N) {
        float a = 0.f;
        int e = rp[n], e1 = rp[n + 1];
        for (; e + 3 < e1; e += 4) {
            int s0 = csr[e], s1 = csr[e + 1], s2 = csr[e + 2], s3 = csr[e + 3];
            a += s[s0] + s[s1] + s[s2] + s[s3];
        }
        for (; e < e1; e++) a += s[csr[e]];
        int g = batch[n];
        atomicAdd(&ls[g], a + t[n]);
        atomicAdd(&lc[g], 1);
    }
    __syncthreads();
    if (tid < NGRAPH && lc[tid] > 0) {
        atomicAdd(&gsum[tid], ls[tid]);
        atomicAdd(&cnt[tid], lc[tid]);
    }
}

__global__ void final_kernel(const float* __restrict__ gsum, const int* __restrict__ cnt,
                             const float* __restrict__ cbuf, const float* __restrict__ head_b,
                             float* __restrict__ out) {
    int g = threadIdx.x;
    if (g < NGRAPH) {
        float c = (float)(cnt[g] > 0 ? cnt[g] : 1);
        out[g] = gsum[g] / c + cbuf[0] + head_b[0];
    }
}

// ---------------- launch ----------------

extern "C" void kernel_launch(void* const* d_in, const int* in_sizes, int n_in,
                              void* d_out, int out_size, void* d_ws, size_t ws_size,
                              hipStream_t stream) {
    const float* x       = (const float*)d_in[0];
    const int*   edge    = (const int*)d_in[1];
    const int*   batch   = (const int*)d_in[2];
    const float* w1_rel  = (const float*)d_in[3];
    const float* w1_root = (const float*)d_in[4];
    const float* b1      = (const float*)d_in[5];
    const float* w2_rel  = (const float*)d_in[6];
    const float* w2_root = (const float*)d_in[7];
    const float* b2      = (const float*)d_in[8];
    const float* w3_rel  = (const float*)d_in[9];
    const float* w3_root = (const float*)d_in[10];
    const float* b3      = (const float*)d_in[11];
    const float* w4_rel  = (const float*)d_in[12];
    const float* w4_root = (const float*)d_in[13];
    const float* b4      = (const float*)d_in[14];
    const float* head_w  = (const float*)d_in[15];
    const float* head_b  = (const float*)d_in[16];
    float* out = (float*)d_out;

    const int N = NNODES, E = NEDGES;
    const int* src = edge;
    const int* dst = edge + E;

    char* ws = (char*)d_ws;
    size_t off = 0;
    auto alloc = [&](size_t bytes) -> char* {
        char* p = ws + off;
        off = (off + bytes + 255) & ~(size_t)255;
        return p;
    };
    // zeroed region first (single small memset): gsum, cnt
    float* gsum  = (float*)alloc(NGRAPH * 4);
    int*   cnt   = (int*)alloc(NGRAPH * 4);
    size_t zero_bytes = off;
    int*   bcnt  = (int*)alloc((size_t)NBUK * NBUK * 4);   // bucket x block counts
    int*   bsum  = (int*)alloc(256 * 4);
    int*   rp    = (int*)alloc((size_t)(N + 1) * 4);
    int*   csr   = (int*)alloc((size_t)E * 4);
    unsigned long long* pedge = (unsigned long long*)alloc((size_t)E * 8);
    unsigned short* xbf    = (unsigned short*)alloc((size_t)N * 128 * 2);
    unsigned short* z1     = (unsigned short*)alloc((size_t)N * 128 * 2);  // [x@w1_rel | x@w1_root]
    unsigned short* combo2 = (unsigned short*)alloc((size_t)N * 128 * 2);  // [agg2 | h1]
    unsigned short* combo3 = (unsigned short*)alloc((size_t)N * 256 * 2);  // [agg3 | h2]
    unsigned short* h3     = (unsigned short*)alloc((size_t)N * 192 * 2);
    unsigned short* pL1    = (unsigned short*)alloc(4 * 8 * 512 * 2);
    unsigned short* pL2    = (unsigned short*)alloc(4 * 8 * 512 * 2);
    unsigned short* pL3    = (unsigned short*)alloc(6 * 16 * 512 * 2);
    float* sbuf  = (float*)alloc((size_t)N * 4);
    float* tbuf  = (float*)alloc((size_t)N * 4);
    float* wr    = (float*)alloc(192 * 4);
    float* wt    = (float*)alloc(192 * 4);
    float* cbuf  = (float*)alloc(4);
    (void)ws_size;

    hipMemsetAsync(gsum, 0, zero_bytes, stream);

    const int TB = 256;

    // CSR build via counting-sort partition
    hist_kernel<<<NBUK, 256, 0, stream>>>(dst, bcnt);
    scan1_kernel<<<NBUK, 256, 0, stream>>>(bcnt, bsum, NBUK * NBUK);
    scan2_kernel<<<1, 256, 0, stream>>>(bsum, NBUK);
    scan3_kernel<<<NBUK, 256, 0, stream>>>(bcnt, bsum, NBUK * NBUK);
    partition_kernel<<<NBUK, 256, 0, stream>>>(src, dst, bcnt, pedge);
    build_kernel<<<NBUK, 256, 0, stream>>>(pedge, bcnt, rp, csr);

    // prep (cvt + pack + head fold in one launch)
    prep_kernel<<<CVT_NB + PACK_NB + 1, 256, 0, stream>>>(
        x, xbf, w1_rel, w1_root, w2_rel, w2_root, w3_rel, w3_root,
        pL1, pL2, pL3, w4_rel, w4_root, b4, head_w, wr, wt, cbuf);

    int ggrid = (N + 127) / 128;

    // L1: z1 = xbf @ [w1_rel | w1_root]
    gemm32_kernel<4, 8><<<ggrid, 256, 0, stream>>>(xbf, pL1, nullptr, z1, 128, 0, 0, N);
    // h1 = relu( nbrsum(z1[:,:64]) + z1[:,64:] + b1 ) -> combo2[:,64:]
    agg_kernel_v2<8><<<(N * 16 + TB - 1) / TB, TB, 0, stream>>>(z1, 128, rp, csr,
                                                                z1 + 64, 128, b1, 1, combo2 + 64, 128, N);
    // agg2 = nbrsum(h1) -> combo2[:,:64]
    agg_kernel_v2<8><<<(N * 16 + TB - 1) / TB, TB, 0, stream>>>(combo2 + 64, 128, rp, csr,
                                                                nullptr, 0, nullptr, 0, combo2, 128, N);
    // L2: h2 = relu(combo2 @ [w2_rel; w2_root] + b2) -> combo3[:,128:]
    gemm32_kernel<4, 8><<<ggrid, 256, 0, stream>>>(combo2, pL2, b2, combo3, 256, 128, 1, N);
    // agg3 = nbrsum(h2) -> combo3[:,:128]
    agg_kernel_v2<16><<<(N * 32 + TB - 1) / TB, TB, 0, stream>>>(combo3 + 128, 256, rp, csr,
                                                                 nullptr, 0, nullptr, 0, combo3, 256, N);
    // L3: h3 = relu(combo3 @ [w3_rel; w3_root] + b3)
    gemm32_kernel<6, 16><<<ggrid, 256, 0, stream>>>(combo3, pL3, b3, h3, 192, 0, 1, N);

    // L4 folded with head
    st_kernel<<<(N * 64 + TB - 1) / TB, TB, 0, stream>>>(h3, wr, wt, sbuf, tbuf, N);
    aggpool_kernel<<<(N + TB - 1) / TB, TB, 0, stream>>>(sbuf, tbuf, rp, csr, batch, gsum, cnt, N);
    final_kernel<<<1, 64, 0, stream>>>(gsum, cnt, cbuf, head_b, out);
}